// Round 6
// baseline (402.296 us; speedup 1.0000x reference)
//
#include <hip/hip_runtime.h>
#include <hip/hip_bf16.h>
#include <math.h>

typedef __hip_bfloat16 bf16;
typedef unsigned short u16;
typedef unsigned int u32;
typedef __attribute__((ext_vector_type(8))) short short8;
typedef __attribute__((ext_vector_type(4))) float f32x4;
typedef __attribute__((ext_vector_type(2))) float f32x2;

#define BATCH 4
#define NNODE 10000
#define TLEN 128
#define NEDGE 160000
#define GDIM 256
#define NHEAD 4
#define XROW 272   // xlb row: 256 feat + 8 (a_s f32x4) + 8 (a_d f32x4) u16 slots

// small-weight fp32 staging offsets (everything except W0/W1/Wa1/Wc1)
#define S_CW1 0
#define S_CB1 96
#define S_CB2 128
#define S_AS0 192
#define S_AD0 448
#define S_B0  704
#define S_AS1 960
#define S_AD1 1216
#define S_B1  1472
#define S_BC1 1728
#define S_WC2 1856
#define S_BC2 2112
#define S_BA1 2114
#define S_WA2 2178
#define S_BA2 2242
#define S_TOTAL 2243

__device__ __forceinline__ float prelu(float v) { return fmaxf(v, 0.f); }
__device__ __forceinline__ u16 f2b(float f) {
    union { float f; u32 u; } v; v.f = f;
    u32 r = v.u + 0x7FFF + ((v.u >> 16) & 1);
    return (u16)(r >> 16);
}
__device__ __forceinline__ float u2f(u16 u) {
    union { u32 u; float f; } v; v.u = ((u32)u) << 16;
    return v.f;
}
__device__ __forceinline__ float ldw(const void* p, int off, bool isbf) {
    return isbf ? u2f(((const u16*)p)[off]) : ((const float*)p)[off];
}

// per-wave inline dtype probes (all waves compute identical results)
__device__ __forceinline__ bool probe_x_bf16(const void* xsrc) {
    int lane = threadIdx.x & 63;
    u16 h = ((const u16*)xsrc)[2 * lane];
    int e = (h >> 7) & 0xFF;
    unsigned long long m = __ballot(e >= 117 && e <= 130);
    return __popcll(m) >= 32;
}
__device__ __forceinline__ bool probe_ei64(const int* ei) {
    int lane = threadIdx.x & 63;
    int v = ei[2 * lane + 1];
    unsigned long long m = __ballot(v == 0);
    return __popcll(m) >= 56;
}

struct WPtrs { const void* p[20]; };

// ------ merged: bf16 transposes + dst histogram + small-weight fp32 staging ------
#define PRE_TBLK 665   // covers max(65536, 170000) indices
__global__ __launch_bounds__(256) void k_pre(WPtrs wp, const void* __restrict__ xsrc,
        const int* __restrict__ ei, float* __restrict__ wbuf,
        u16* __restrict__ cw2r, u16* __restrict__ W0t, u16* __restrict__ W1t,
        u16* __restrict__ Wa1t, int* __restrict__ counts) {
    bool isbf = probe_x_bf16(xsrc);
    int b = blockIdx.x;
    if (b >= PRE_TBLK) {   // small-weight staging (9 blocks)
        const int C2[16] = {0,96,128,192,448,704,960,1216,1472,1728,1856,2112,
                            2114,2178,2242,2243};
        const int SRC[15] = {0,1,3,5,6,7,9,10,11,13,14,15,17,18,19};
        int i = (b - PRE_TBLK) * 256 + threadIdx.x;
        if (i >= S_TOTAL) return;
        int j = 14;
        for (int t = 0; t < 15; ++t) { if (i < C2[t + 1]) { j = t; break; } }
        wbuf[i] = ldw(wp.p[SRC[j]], i - C2[j], isbf);
        return;
    }
    int i = b * 256 + threadIdx.x;
    if (i < 6144) {   // cw2r[c2][k'=dk*32+ci]
        int c2 = i / 96, k = i - c2 * 96, s = k >> 5, ci = k & 31;
        cw2r[i] = f2b(ldw(wp.p[2], c2 * 96 + ci * 3 + s, isbf));
    }
    if (i < 16384) {  // W0t / Wa1t, coalesced reads
        int k = i >> 8, c = i & 255;
        W0t[c * 64 + k] = f2b(ldw(wp.p[4], k * 256 + c, isbf));
        int ka = i >> 6, ca = i & 63;
        Wa1t[ca * 256 + ka] = f2b(ldw(wp.p[16], ka * 64 + ca, isbf));
    }
    if (i < 65536) {  // W1t
        int k = i >> 8, c = i & 255;
        W1t[c * 256 + k] = f2b(ldw(wp.p[8], k * 256 + c, isbf));
    }
    if (i < NEDGE + NNODE) {   // dst histogram (counts pre-zeroed by memset)
        bool ei64 = probe_ei64(ei);
        int dst;
        if (i < NEDGE) dst = ei64 ? ei[2 * (NEDGE + i)] : ei[NEDGE + i];
        else dst = i - NEDGE;
        if (dst >= 0 && dst < NNODE) atomicAdd(&counts[dst], 1);
    }
}

// ---------------- single-block scan (replaces scan1+scan3) ----------------
__global__ __launch_bounds__(1024) void k_scan(const int* __restrict__ counts,
        int* __restrict__ cur, int* __restrict__ row_ptr) {
    __shared__ int buf[1024];
    int t = threadIdx.x;
    int base = t * 10;
    int c[10];
    int s = 0;
    #pragma unroll
    for (int i = 0; i < 10; ++i) {
        int idx = base + i;
        c[i] = (idx < NNODE) ? counts[idx] : 0;
        s += c[i];
    }
    buf[t] = s;
    __syncthreads();
    for (int off = 1; off < 1024; off <<= 1) {
        int v = (t >= off) ? buf[t - off] : 0;
        __syncthreads();
        buf[t] += v;
        __syncthreads();
    }
    int run = buf[t] - s;   // exclusive prefix of this thread's chunk
    #pragma unroll
    for (int i = 0; i < 10; ++i) {
        int idx = base + i;
        if (idx < NNODE) {
            cur[idx] = run;
            run += c[i];
            row_ptr[idx + 1] = run;
        }
    }
    if (t == 0) row_ptr[0] = 0;
}

// ---- fused temporal conv + CSR fill; SOLO-WAVE (R5 structure, unchanged) ----
#define HSTR 40
#define NPW 4
#define FILL_BLK 665
__global__ __launch_bounds__(256) void k_conv(const void* __restrict__ xsrc,
        const float* __restrict__ wbuf, const u16* __restrict__ cw2r,
        u16* __restrict__ featb, const int* __restrict__ ei,
        int* __restrict__ cur, int* __restrict__ col_src) {
    __shared__ __align__(16) float xs[4][132];
    __shared__ float w1s[96], b1s[32], b2s[64];
    __shared__ __align__(16) u16 hb[4][66 * HSTR];   // per-wave private slices

    bool isbf = probe_x_bf16(xsrc);
    int tid = threadIdx.x;
    int wave = tid >> 6, lane = tid & 63;
    int node0 = blockIdx.x * (4 * NPW);

    int m = lane & 15, q = lane >> 4;
    short8 bfr[4][3];
    #pragma unroll
    for (int nt = 0; nt < 4; ++nt)
        #pragma unroll
        for (int sh = 0; sh < 3; ++sh)
            bfr[nt][sh] = *(const short8*)&cw2r[(nt * 16 + m) * 96 + sh * 32 + q * 8];

    if (tid < 96) w1s[tid] = wbuf[S_CW1 + tid];
    if (tid < 32) b1s[tid] = wbuf[S_CB1 + tid];
    if (tid < 64) b2s[tid] = wbuf[S_CB2 + tid];
    if (tid < 8) xs[tid >> 1][(tid & 1) ? 129 : 0] = 0.f;
    if (tid < 64) {
        int w = tid >> 4, idx = tid & 15;
        *(u32*)&hb[w][2 * idx] = 0;
        *(u32*)&hb[w][65 * HSTR + 2 * idx] = 0;
    }
    __syncthreads();   // the ONLY barrier in this kernel

    float* xsw = xs[wave];
    u16* hw = &hb[wave][0];

    int d = m, uu = q;
    float wa0 = w1s[6 * d + 0], wa1 = w1s[6 * d + 1], wa2 = w1s[6 * d + 2];
    float wb0 = w1s[6 * d + 3], wb1 = w1s[6 * d + 4], wb2 = w1s[6 * d + 5];
    float ba = b1s[2 * d], bb = b1s[2 * d + 1];
    float b2vv[4];
    #pragma unroll
    for (int nt = 0; nt < 4; ++nt) b2vv[nt] = b2s[nt * 16 + m];

    int node = node0 + wave;
    u32 plo = 0; float2 pf = {0.f, 0.f};
    if (isbf) plo = ((const u32*)xsrc)[(size_t)node * 64 + lane];
    else      pf  = ((const float2*)xsrc)[(size_t)node * 64 + lane];

    for (int j = 0; j < NPW; ++j) {
        if (isbf) {
            xsw[1 + 2 * lane] = u2f((u16)(plo & 0xFFFF));
            xsw[2 + 2 * lane] = u2f((u16)(plo >> 16));
        } else {
            xsw[1 + 2 * lane] = pf.x;
            xsw[2 + 2 * lane] = pf.y;
        }
        if (j + 1 < NPW) {
            int nxt = node + 4;
            if (isbf) plo = ((const u32*)xsrc)[(size_t)nxt * 64 + lane];
            else      pf  = ((const float2*)xsrc)[(size_t)nxt * 64 + lane];
        }

        #pragma unroll
        for (int it = 0; it < 16; ++it) {
            int u = uu + 4 * it;
            int t0 = 2 * u;
            float2 xa = *(const float2*)&xsw[t0];
            float2 xb = *(const float2*)&xsw[t0 + 2];
            float x0 = xa.x, x1 = xa.y, x2 = xb.x, x3 = xb.y;
            f32x2 A = {x0, x1}, Bv = {x1, x2}, Cv = {x2, x3};
            f32x2 va = {ba, ba}; va += wa0 * A; va += wa1 * Bv; va += wa2 * Cv;
            f32x2 vb = {bb, bb}; vb += wb0 * A; vb += wb1 * Bv; vb += wb2 * Cv;
            float ha = fmaxf(fmaxf(va.x, va.y), 0.f);
            float hb2 = fmaxf(fmaxf(vb.x, vb.y), 0.f);
            __hip_bfloat162 hp2 = __float22bfloat162_rn(make_float2(ha, hb2));
            u32 pack; __builtin_memcpy(&pack, &hp2, 4);
            *(u32*)&hw[(u + 1) * HSTR + 2 * d] = pack;
        }

        float pc0 = 0.f, pc1 = 0.f, pc2 = 0.f, pc3 = 0.f;
        #pragma unroll
        for (int mt = 0; mt < 4; ++mt) {
            const u16* hr = &hw[(mt * 16 + m) * HSTR + q * 8];
            short8 a0 = *(const short8*)&hr[0 * HSTR];
            short8 a1 = *(const short8*)&hr[1 * HSTR];
            short8 a2 = *(const short8*)&hr[2 * HSTR];
            f32x4 c0 = {0.f,0.f,0.f,0.f}, c1 = {0.f,0.f,0.f,0.f};
            f32x4 c2 = {0.f,0.f,0.f,0.f}, c3 = {0.f,0.f,0.f,0.f};
            c0 = __builtin_amdgcn_mfma_f32_16x16x32_bf16(a0, bfr[0][0], c0, 0, 0, 0);
            c1 = __builtin_amdgcn_mfma_f32_16x16x32_bf16(a0, bfr[1][0], c1, 0, 0, 0);
            c2 = __builtin_amdgcn_mfma_f32_16x16x32_bf16(a0, bfr[2][0], c2, 0, 0, 0);
            c3 = __builtin_amdgcn_mfma_f32_16x16x32_bf16(a0, bfr[3][0], c3, 0, 0, 0);
            c0 = __builtin_amdgcn_mfma_f32_16x16x32_bf16(a1, bfr[0][1], c0, 0, 0, 0);
            c1 = __builtin_amdgcn_mfma_f32_16x16x32_bf16(a1, bfr[1][1], c1, 0, 0, 0);
            c2 = __builtin_amdgcn_mfma_f32_16x16x32_bf16(a1, bfr[2][1], c2, 0, 0, 0);
            c3 = __builtin_amdgcn_mfma_f32_16x16x32_bf16(a1, bfr[3][1], c3, 0, 0, 0);
            c0 = __builtin_amdgcn_mfma_f32_16x16x32_bf16(a2, bfr[0][2], c0, 0, 0, 0);
            c1 = __builtin_amdgcn_mfma_f32_16x16x32_bf16(a2, bfr[1][2], c1, 0, 0, 0);
            c2 = __builtin_amdgcn_mfma_f32_16x16x32_bf16(a2, bfr[2][2], c2, 0, 0, 0);
            c3 = __builtin_amdgcn_mfma_f32_16x16x32_bf16(a2, bfr[3][2], c3, 0, 0, 0);
            pc0 += prelu(c0[0] + b2vv[0]) + prelu(c0[1] + b2vv[0])
                 + prelu(c0[2] + b2vv[0]) + prelu(c0[3] + b2vv[0]);
            pc1 += prelu(c1[0] + b2vv[1]) + prelu(c1[1] + b2vv[1])
                 + prelu(c1[2] + b2vv[1]) + prelu(c1[3] + b2vv[1]);
            pc2 += prelu(c2[0] + b2vv[2]) + prelu(c2[1] + b2vv[2])
                 + prelu(c2[2] + b2vv[2]) + prelu(c2[3] + b2vv[2]);
            pc3 += prelu(c3[0] + b2vv[3]) + prelu(c3[1] + b2vv[3])
                 + prelu(c3[2] + b2vv[3]) + prelu(c3[3] + b2vv[3]);
        }
        pc0 += __shfl_xor(pc0, 16, 64); pc0 += __shfl_xor(pc0, 32, 64);
        pc1 += __shfl_xor(pc1, 16, 64); pc1 += __shfl_xor(pc1, 32, 64);
        pc2 += __shfl_xor(pc2, 16, 64); pc2 += __shfl_xor(pc2, 32, 64);
        pc3 += __shfl_xor(pc3, 16, 64); pc3 += __shfl_xor(pc3, 32, 64);
        float v = (q == 0) ? pc0 : (q == 1) ? pc1 : (q == 2) ? pc2 : pc3;
        int bb2 = node / NNODE, nn = node - bb2 * NNODE;
        featb[((size_t)nn * 4 + bb2) * 64 + lane] = f2b(v * (1.f / 64.f));

        node += 4;
    }

    // ---- CSR fill slice (blocks < FILL_BLK) ----
    if (blockIdx.x < FILL_BLK) {
        bool ei64 = probe_ei64(ei);
        int e = blockIdx.x * 256 + tid;
        if (e < NEDGE + NNODE) {
            int src, dst;
            if (e < NEDGE) {
                if (ei64) { src = ei[2 * e]; dst = ei[2 * (NEDGE + e)]; }
                else      { src = ei[e];     dst = ei[NEDGE + e]; }
            } else {
                src = dst = e - NEDGE;
            }
            if (dst >= 0 && dst < NNODE) {
                int pos = atomicAdd(&cur[dst], 1);
                if (pos >= 0 && pos < NEDGE + NNODE) col_src[pos] = src;
            }
        }
    }
}

// ------ zero-LDS MFMA GEMM (MT=1); attention scores COLOCATED in xlb row tails ------
template<int K>
__global__ __launch_bounds__(256) void k_gemm(const u16* __restrict__ A,
        const u16* __restrict__ Wt, const float* __restrict__ att_s_w,
        const float* __restrict__ att_d_w, u16* __restrict__ outb) {
    int wave = threadIdx.x >> 6, lane = threadIdx.x & 63;
    int row0 = (blockIdx.x * 4 + wave) * 16;
    int m = lane & 15, q = lane >> 4;
    f32x4 acc[16];
    #pragma unroll
    for (int nt = 0; nt < 16; ++nt) acc[nt] = {0.f, 0.f, 0.f, 0.f};
    for (int kc = 0; kc < K; kc += 32) {
        short8 a = *(const short8*)&A[(size_t)(row0 + m) * K + kc + q * 8];
        #pragma unroll
        for (int nt = 0; nt < 16; ++nt) {
            short8 b = *(const short8*)&Wt[(size_t)(nt * 16 + m) * K + kc + q * 8];
            acc[nt] = __builtin_amdgcn_mfma_f32_16x16x32_bf16(a, b, acc[nt], 0, 0, 0);
        }
    }
    #pragma unroll
    for (int nt = 0; nt < 16; ++nt) {
        #pragma unroll
        for (int r = 0; r < 4; ++r)
            outb[(size_t)(row0 + q * 4 + r) * XROW + nt * 16 + m] = f2b(acc[nt][r]);
    }
    float sh_s[4][4] = {{0}}, sh_d[4][4] = {{0}};
    #pragma unroll
    for (int nt = 0; nt < 16; ++nt) {
        int h = nt >> 2;
        int cc = (nt & 3) * 16 + m;
        float asw = att_s_w[h * 64 + cc];
        float adw = att_d_w[h * 64 + cc];
        #pragma unroll
        for (int r = 0; r < 4; ++r) {
            sh_s[h][r] += acc[nt][r] * asw;
            sh_d[h][r] += acc[nt][r] * adw;
        }
    }
    #pragma unroll
    for (int off = 1; off < 16; off <<= 1) {
        #pragma unroll
        for (int h = 0; h < 4; ++h)
            #pragma unroll
            for (int r = 0; r < 4; ++r) {
                sh_s[h][r] += __shfl_xor(sh_s[h][r], off, 64);
                sh_d[h][r] += __shfl_xor(sh_d[h][r], off, 64);
            }
    }
    if (m == 0) {
        #pragma unroll
        for (int r = 0; r < 4; ++r) {
            int row = row0 + q * 4 + r;
            float4 vs = {sh_s[0][r], sh_s[1][r], sh_s[2][r], sh_s[3][r]};
            float4 vd = {sh_d[0][r], sh_d[1][r], sh_d[2][r], sh_d[3][r]};
            *(float4*)&outb[(size_t)row * XROW + 256] = vs;   // a_s tail (16B-aligned)
            *(float4*)&outb[(size_t)row * XROW + 264] = vd;   // a_d tail
        }
    }
}

// ---------------- GAT aggregation: single-pass online softmax ----------------
// a_s/a_d read from xlb row TAILS (same cache lines as the feature gather);
// col_src preloaded one chunk ahead to break the per-chunk load dependency.
__global__ __launch_bounds__(256) void k_agg(const u16* __restrict__ xlb,
        const int* __restrict__ row_ptr, const int* __restrict__ col_src,
        const float* __restrict__ bias, u16* __restrict__ gb_out) {
    int wave = threadIdx.x >> 6, lane = threadIdx.x & 63;
    int dst = __builtin_amdgcn_readfirstlane(blockIdx.x * 2 + (wave >> 1));
    int bp = (wave & 1) * 2;
    int beg = __builtin_amdgcn_readfirstlane(row_ptr[dst]);
    int end = __builtin_amdgcn_readfirstlane(row_ptr[dst + 1]);

    int bl = lane >> 5;
    int s = lane & 31;
    int h = s >> 3;
    int b = bp + bl;
    float advh = *(const float*)&xlb[((size_t)dst * 4 + b) * XROW + 264 + h * 2];

    float m = -INFINITY, l = 0.f;
    float acc[8];
    #pragma unroll
    for (int k = 0; k < 8; ++k) acc[k] = 0.f;

    int i = beg;
    int n0 = 0, n1 = 0, n2 = 0, n3 = 0;
    if (i + 4 <= end) {
        n0 = col_src[i]; n1 = col_src[i + 1];
        n2 = col_src[i + 2]; n3 = col_src[i + 3];
    }
    while (i + 4 <= end) {
        int s0 = min(max(n0, 0), NNODE - 1);
        int s1 = min(max(n1, 0), NNODE - 1);
        int s2 = min(max(n2, 0), NNODE - 1);
        int s3 = min(max(n3, 0), NNODE - 1);
        const u16* r0 = &xlb[((size_t)s0 * 4 + b) * XROW];
        const u16* r1 = &xlb[((size_t)s1 * 4 + b) * XROW];
        const u16* r2 = &xlb[((size_t)s2 * 4 + b) * XROW];
        const u16* r3 = &xlb[((size_t)s3 * 4 + b) * XROW];
        float a0 = *(const float*)&r0[256 + h * 2];
        float a1 = *(const float*)&r1[256 + h * 2];
        float a2 = *(const float*)&r2[256 + h * 2];
        float a3 = *(const float*)&r3[256 + h * 2];
        short8 x0 = *(const short8*)&r0[s * 8];
        short8 x1 = *(const short8*)&r1[s * 8];
        short8 x2 = *(const short8*)&r2[s * 8];
        short8 x3 = *(const short8*)&r3[s * 8];
        i += 4;
        if (i + 4 <= end) {   // preload next chunk's col_src (hides its latency)
            n0 = col_src[i]; n1 = col_src[i + 1];
            n2 = col_src[i + 2]; n3 = col_src[i + 3];
        }
        float e0 = a0 + advh; e0 = (e0 >= 0.f) ? e0 : 0.2f * e0;
        float e1 = a1 + advh; e1 = (e1 >= 0.f) ? e1 : 0.2f * e1;
        float e2 = a2 + advh; e2 = (e2 >= 0.f) ? e2 : 0.2f * e2;
        float e3 = a3 + advh; e3 = (e3 >= 0.f) ? e3 : 0.2f * e3;
        float cmax = fmaxf(fmaxf(e0, e1), fmaxf(e2, e3));
        if (__any(cmax > m)) {      // wave-uniform, rare after warmup
            float mn = fmaxf(m, cmax);
            float r = __expf(m - mn);
            m = mn;
            l *= r;
            #pragma unroll
            for (int k = 0; k < 8; ++k) acc[k] *= r;
        }
        float p0 = __expf(e0 - m); l += p0;
        #pragma unroll
        for (int k = 0; k < 8; ++k) acc[k] += p0 * u2f((u16)x0[k]);
        float p1 = __expf(e1 - m); l += p1;
        #pragma unroll
        for (int k = 0; k < 8; ++k) acc[k] += p1 * u2f((u16)x1[k]);
        float p2 = __expf(e2 - m); l += p2;
        #pragma unroll
        for (int k = 0; k < 8; ++k) acc[k] += p2 * u2f((u16)x2[k]);
        float p3 = __expf(e3 - m); l += p3;
        #pragma unroll
        for (int k = 0; k < 8; ++k) acc[k] += p3 * u2f((u16)x3[k]);
    }
    for (; i < end; ++i) {
        int s0 = min(max(col_src[i], 0), NNODE - 1);
        const u16* r0 = &xlb[((size_t)s0 * 4 + b) * XROW];
        float a0 = *(const float*)&r0[256 + h * 2];
        short8 x0 = *(const short8*)&r0[s * 8];
        float e0 = a0 + advh; e0 = (e0 >= 0.f) ? e0 : 0.2f * e0;
        if (__any(e0 > m)) {
            float mn = fmaxf(m, e0);
            float r = __expf(m - mn);
            m = mn;
            l *= r;
            #pragma unroll
            for (int k = 0; k < 8; ++k) acc[k] *= r;
        }
        float p0 = __expf(e0 - m); l += p0;
        #pragma unroll
        for (int k = 0; k < 8; ++k) acc[k] += p0 * u2f((u16)x0[k]);
    }

    float rl = 1.f / (l + 1e-16f);
    short8 o;
    #pragma unroll
    for (int k = 0; k < 8; ++k)
        o[k] = (short)f2b(prelu(acc[k] * rl + bias[s * 8 + k]));
    *(short8*)&gb_out[((size_t)dst * 4 + b) * 256 + s * 8] = o;
}

// ---------------- attribution head (blocks <625) + pooled sum (blocks >=625) ----------
__global__ __launch_bounds__(256) void k_attrpool(const u16* __restrict__ gb,
        const u16* __restrict__ Wa1t, const float* __restrict__ wbuf,
        float* __restrict__ out, float* __restrict__ pooled) {
    if (blockIdx.x >= 625) {   // pool part, n-loop unrolled x4 (independent loads)
        int pb = blockIdx.x - 625;
        int b = pb >> 6;
        int chunk = pb & 63;
        int cch = threadIdx.x;
        int n0 = chunk * 157;
        int n1 = min(NNODE, n0 + 157);
        float acc = 0.f;
        int n = n0;
        for (; n + 4 <= n1; n += 4) {
            float v0 = u2f(gb[((size_t)n * 4 + b) * 256 + cch]);
            float v1 = u2f(gb[((size_t)(n + 1) * 4 + b) * 256 + cch]);
            float v2 = u2f(gb[((size_t)(n + 2) * 4 + b) * 256 + cch]);
            float v3 = u2f(gb[((size_t)(n + 3) * 4 + b) * 256 + cch]);
            acc += v0; acc += v1; acc += v2; acc += v3;
        }
        for (; n < n1; ++n)
            acc += u2f(gb[((size_t)n * 4 + b) * 256 + cch]);
        atomicAdd(&pooled[b * 256 + cch], acc);
        return;
    }
    int wave = threadIdx.x >> 6, lane = threadIdx.x & 63;
    int row0 = (blockIdx.x * 4 + wave) * 16;
    int m = lane & 15, q = lane >> 4;
    f32x4 acc[4];
    #pragma unroll
    for (int nt = 0; nt < 4; ++nt) acc[nt] = {0.f, 0.f, 0.f, 0.f};
    for (int kc = 0; kc < 256; kc += 32) {
        short8 a = *(const short8*)&gb[(size_t)(row0 + m) * 256 + kc + q * 8];
        #pragma unroll
        for (int nt = 0; nt < 4; ++nt) {
            short8 b = *(const short8*)&Wa1t[(size_t)(nt * 16 + m) * 256 + kc + q * 8];
            acc[nt] = __builtin_amdgcn_mfma_f32_16x16x32_bf16(a, b, acc[nt], 0, 0, 0);
        }
    }
    float part[4] = {0, 0, 0, 0};
    #pragma unroll
    for (int nt = 0; nt < 4; ++nt) {
        int col = nt * 16 + m;
        float ba1v = wbuf[S_BA1 + col];
        float wa2v = wbuf[S_WA2 + col];
        #pragma unroll
        for (int r = 0; r < 4; ++r)
            part[r] += prelu(acc[nt][r] + ba1v) * wa2v;
    }
    #pragma unroll
    for (int off = 1; off < 16; off <<= 1) {
        #pragma unroll
        for (int r = 0; r < 4; ++r)
            part[r] += __shfl_xor(part[r], off, 64);
    }
    if (m == 0) {
        float ba2v = wbuf[S_BA2];
        #pragma unroll
        for (int r = 0; r < 4; ++r) {
            int row = row0 + q * 4 + r;
            int n = row >> 2, b = row & 3;
            float v = part[r] + ba2v;
            out[8 + b * NNODE + n] = 1.f / (1.f + __expf(-v));
        }
    }
}

// ---------------- classification head (blocks 0-3) + diagnostics (block 4) ----------
__global__ __launch_bounds__(128) void k_logits(const float* __restrict__ pooled,
        const float* __restrict__ wbuf, const void* __restrict__ Wc1p,
        float* __restrict__ out,
        const u16* __restrict__ featb, const u16* __restrict__ gb,
        const int* __restrict__ row_ptr, const int* __restrict__ ei,
        const void* __restrict__ xsrc, int hostbad) {
    int tid = threadIdx.x;
    bool isbf = probe_x_bf16(xsrc);
    if (blockIdx.x == 4) {   // sampled diagnostics
        __shared__ float red[128];
        bool ei64 = probe_ei64(ei);
        float mx[2] = {0.f, 0.f};
        const u16* bufs[2] = {featb, gb};
        for (int qq = 0; qq < 2; ++qq) {
            const u16* p = bufs[qq];
            float m = 0.f;
            for (int i = tid; i < 2048; i += 128) {
                float v = u2f(p[i]);
                if (v != v) m = 1e30f;
                m = fmaxf(m, fabsf(v));
            }
            red[tid] = m;
            __syncthreads();
            for (int s2 = 64; s2 > 0; s2 >>= 1) {
                if (tid < s2) red[tid] = fmaxf(red[tid], red[tid + s2]);
                __syncthreads();
            }
            mx[qq] = red[0];
            __syncthreads();
        }
        if (tid == 0) {
            int fb = (mx[0] > 1e8f || mx[0] < 1e-6f) ? 1 : 0;
            int gbad = (mx[1] > 1e8f || mx[1] < 1e-6f) ? 1 : 0;
            int cb = (row_ptr[NNODE] != NEDGE + NNODE) ? 1 : 0;
            int code = 100 * fb + 400 * gbad + 800 * cb + 6400 * hostbad;
            if (code) {
                code += 1600 * (isbf ? 0 : 1);
                code += 3200 * (ei64 ? 1 : 0);
                for (int j = 0; j < 8; ++j) out[j] = (float)code;
            }
        }
        return;
    }
    __shared__ float pm[256];
    __shared__ float red4[4];
    int b = blockIdx.x;
    pm[tid] = pooled[b * 256 + tid] * (1.f / NNODE);
    pm[tid + 128] = pooled[b * 256 + tid + 128] * (1.f / NNODE);
    __syncthreads();
    float acc = wbuf[S_BC1 + tid];
    if (isbf) {
        const u16* w = (const u16*)Wc1p;
        #pragma unroll 4
        for (int k = 0; k < 256; ++k)
            acc += pm[k] * u2f(w[k * 128 + tid]);
    } else {
        const float* w = (const float*)Wc1p;
        #pragma unroll 4
        for (int k = 0; k < 256; ++k)
            acc += pm[k] * w[k * 128 + tid];
    }
    float hv = prelu(acc);
    float p0 = hv * wbuf[S_WC2 + tid * 2];
    float p1 = hv * wbuf[S_WC2 + tid * 2 + 1];
    #pragma unroll
    for (int off = 32; off > 0; off >>= 1) {
        p0 += __shfl_xor(p0, off, 64);
        p1 += __shfl_xor(p1, off, 64);
    }
    int wv = tid >> 6, lane = tid & 63;
    if (lane == 0) { red4[wv * 2] = p0; red4[wv * 2 + 1] = p1; }
    __syncthreads();
    if (tid < 2)
        out[b * 2 + tid] = red4[tid] + red4[2 + tid] + wbuf[S_BC2 + tid];
}

extern "C" void kernel_launch(void* const* d_in, const int* in_sizes, int n_in,
                              void* d_out, int out_size, void* d_ws, size_t ws_size,
                              hipStream_t stream) {
    const void* x  = d_in[0];
    const int*  ei = (const int*)d_in[1];
    float* out = (float*)d_out;

    WPtrs wp;
    for (int j = 0; j < 20; ++j) wp.p[j] = d_in[j + 2];

    char* ws = (char*)d_ws;
    size_t off = 0;
    auto alloc = [&](size_t bytes) -> void* {
        void* p = ws + off;
        off += (bytes + 255) & ~(size_t)255;
        return p;
    };
    float* wbuf    = (float*)alloc((size_t)S_TOTAL * 4);
    u16*   featb   = (u16*)  alloc((size_t)BATCH * NNODE * 64 * 2);
    u16*   xlb     = (u16*)  alloc((size_t)BATCH * NNODE * XROW * 2);
    u16*   gb      = (u16*)  alloc((size_t)BATCH * NNODE * 256 * 2);
    u16*   cw2r    = (u16*)alloc(6144 * 2);
    u16*   W0t     = (u16*)alloc(16384 * 2);
    u16*   W1t     = (u16*)alloc(65536 * 2);
    u16*   Wa1t    = (u16*)alloc(16384 * 2);
    // counts and pooled ADJACENT: one memset zeroes both
    int*   counts  = (int*)alloc(NNODE * 4);           // padded to 40192
    float* pooled  = (float*)alloc(BATCH * 256 * 4);   // 4096
    int*   row_ptr = (int*)alloc((NNODE + 1) * 4);
    int*   cur     = (int*)alloc(NNODE * 4);
    int*   col_src = (int*)alloc((NEDGE + NNODE) * 4);
    (void)ws_size; (void)out_size;

    int hostbad = (n_in != 22 || in_sizes[0] != BATCH * NNODE * TLEN ||
                   in_sizes[1] != 2 * NEDGE) ? 1 : 0;

    hipMemsetAsync(counts, 0, 40192 + 4096, stream);

    k_pre<<<PRE_TBLK + 9, 256, 0, stream>>>(wp, x, ei, wbuf, cw2r, W0t, W1t, Wa1t, counts);
    k_scan<<<1, 1024, 0, stream>>>(counts, cur, row_ptr);

    // conv + CSR fill fused (solo-wave, 4 nodes/wave, zero inner barriers)
    k_conv<<<BATCH * NNODE / (4 * NPW), 256, 0, stream>>>(x, wbuf, cw2r, featb, ei, cur, col_src);

    // GAT layer 0
    k_gemm<64><<<BATCH * NNODE / 64, 256, 0, stream>>>(featb, W0t,
            wbuf + S_AS0, wbuf + S_AD0, xlb);
    k_agg<<<NNODE / 2, 256, 0, stream>>>(xlb, row_ptr, col_src, wbuf + S_B0, gb);

    // GAT layer 1
    k_gemm<256><<<BATCH * NNODE / 64, 256, 0, stream>>>(gb, W1t,
            wbuf + S_AS1, wbuf + S_AD1, xlb);
    k_agg<<<NNODE / 2, 256, 0, stream>>>(xlb, row_ptr, col_src, wbuf + S_B1, gb);

    // heads
    k_attrpool<<<625 + 256, 256, 0, stream>>>(gb, Wa1t, wbuf, out, pooled);
    k_logits<<<5, 128, 0, stream>>>(pooled, wbuf, wp.p[12], out, featb, gb, row_ptr, ei, x, hostbad);
}

// Round 8
// 389.708 us; speedup vs baseline: 1.0323x; 1.0323x over previous
//
#include <hip/hip_runtime.h>
#include <hip/hip_bf16.h>
#include <math.h>

typedef __hip_bfloat16 bf16;
typedef unsigned short u16;
typedef unsigned int u32;
typedef __attribute__((ext_vector_type(8))) short short8;
typedef __attribute__((ext_vector_type(4))) float f32x4;
typedef __attribute__((ext_vector_type(2))) float f32x2;

#define BATCH 4
#define NNODE 10000
#define TLEN 128
#define NEDGE 160000
#define GDIM 256
#define NHEAD 4

// small-weight fp32 staging offsets (everything except W0/W1/Wa1/Wc1)
#define S_CW1 0
#define S_CB1 96
#define S_CB2 128
#define S_AS0 192
#define S_AD0 448
#define S_B0  704
#define S_AS1 960
#define S_AD1 1216
#define S_B1  1472
#define S_BC1 1728
#define S_WC2 1856
#define S_BC2 2112
#define S_BA1 2114
#define S_WA2 2178
#define S_BA2 2242
#define S_TOTAL 2243

__device__ __forceinline__ float prelu(float v) { return fmaxf(v, 0.f); }
__device__ __forceinline__ u16 f2b(float f) {
    union { float f; u32 u; } v; v.f = f;
    u32 r = v.u + 0x7FFF + ((v.u >> 16) & 1);
    return (u16)(r >> 16);
}
__device__ __forceinline__ float u2f(u16 u) {
    union { u32 u; float f; } v; v.u = ((u32)u) << 16;
    return v.f;
}
__device__ __forceinline__ float ldw(const void* p, int off, bool isbf) {
    return isbf ? u2f(((const u16*)p)[off]) : ((const float*)p)[off];
}

// per-wave inline dtype probes (all waves compute identical results)
__device__ __forceinline__ bool probe_x_bf16(const void* xsrc) {
    int lane = threadIdx.x & 63;
    u16 h = ((const u16*)xsrc)[2 * lane];
    int e = (h >> 7) & 0xFF;
    unsigned long long m = __ballot(e >= 117 && e <= 130);
    return __popcll(m) >= 32;
}
__device__ __forceinline__ bool probe_ei64(const int* ei) {
    int lane = threadIdx.x & 63;
    int v = ei[2 * lane + 1];
    unsigned long long m = __ballot(v == 0);
    return __popcll(m) >= 56;
}

struct WPtrs { const void* p[20]; };

// ------ merged: bf16 transposes + dst histogram + small-weight fp32 staging ------
#define PRE_TBLK 665   // covers max(65536, 170000) indices
__global__ __launch_bounds__(256) void k_pre(WPtrs wp, const void* __restrict__ xsrc,
        const int* __restrict__ ei, float* __restrict__ wbuf,
        u16* __restrict__ cw2r, u16* __restrict__ W0t, u16* __restrict__ W1t,
        u16* __restrict__ Wa1t, int* __restrict__ counts) {
    bool isbf = probe_x_bf16(xsrc);
    int b = blockIdx.x;
    if (b >= PRE_TBLK) {   // small-weight staging (9 blocks)
        const int C2[16] = {0,96,128,192,448,704,960,1216,1472,1728,1856,2112,
                            2114,2178,2242,2243};
        const int SRC[15] = {0,1,3,5,6,7,9,10,11,13,14,15,17,18,19};
        int i = (b - PRE_TBLK) * 256 + threadIdx.x;
        if (i >= S_TOTAL) return;
        int j = 14;
        for (int t = 0; t < 15; ++t) { if (i < C2[t + 1]) { j = t; break; } }
        wbuf[i] = ldw(wp.p[SRC[j]], i - C2[j], isbf);
        return;
    }
    int i = b * 256 + threadIdx.x;
    if (i < 6144) {   // cw2r[c2][k'=dk*32+ci]
        int c2 = i / 96, k = i - c2 * 96, s = k >> 5, ci = k & 31;
        cw2r[i] = f2b(ldw(wp.p[2], c2 * 96 + ci * 3 + s, isbf));
    }
    if (i < 16384) {  // W0t / Wa1t, coalesced reads
        int k = i >> 8, c = i & 255;
        W0t[c * 64 + k] = f2b(ldw(wp.p[4], k * 256 + c, isbf));
        int ka = i >> 6, ca = i & 63;
        Wa1t[ca * 256 + ka] = f2b(ldw(wp.p[16], ka * 64 + ca, isbf));
    }
    if (i < 65536) {  // W1t
        int k = i >> 8, c = i & 255;
        W1t[c * 256 + k] = f2b(ldw(wp.p[8], k * 256 + c, isbf));
    }
    if (i < NEDGE + NNODE) {   // dst histogram (counts pre-zeroed by memset)
        bool ei64 = probe_ei64(ei);
        int dst;
        if (i < NEDGE) dst = ei64 ? ei[2 * (NEDGE + i)] : ei[NEDGE + i];
        else dst = i - NEDGE;
        if (dst >= 0 && dst < NNODE) atomicAdd(&counts[dst], 1);
    }
}

// ---------------- single-block scan ----------------
__global__ __launch_bounds__(1024) void k_scan(const int* __restrict__ counts,
        int* __restrict__ cur, int* __restrict__ row_ptr) {
    __shared__ int buf[1024];
    int t = threadIdx.x;
    int base = t * 10;
    int c[10];
    int s = 0;
    #pragma unroll
    for (int i = 0; i < 10; ++i) {
        int idx = base + i;
        c[i] = (idx < NNODE) ? counts[idx] : 0;
        s += c[i];
    }
    buf[t] = s;
    __syncthreads();
    for (int off = 1; off < 1024; off <<= 1) {
        int v = (t >= off) ? buf[t - off] : 0;
        __syncthreads();
        buf[t] += v;
        __syncthreads();
    }
    int run = buf[t] - s;   // exclusive prefix of this thread's chunk
    #pragma unroll
    for (int i = 0; i < 10; ++i) {
        int idx = base + i;
        if (idx < NNODE) {
            cur[idx] = run;
            run += c[i];
            row_ptr[idx + 1] = run;
        }
    }
    if (t == 0) row_ptr[0] = 0;
}

// ---- fused temporal conv + GAT-0 GEMM + CSR fill. Solo-wave conv (R5), then
// one barrier, then gemm<64> off the LDS feat tile: block's 16 consecutive
// (batch-major) nodes = one 16-row M-tile; wave w owns cols [w*64,w*64+64)
// = exactly head h=w, so attention scores need no cross-wave reduce. ----
#define HSTR 40
#define FSTR 72
#define NPW 4
#define FILL_BLK 665
__global__ __launch_bounds__(256) void k_conv(const void* __restrict__ xsrc,
        const float* __restrict__ wbuf, const u16* __restrict__ cw2r,
        const u16* __restrict__ W0t, u16* __restrict__ featb,
        u16* __restrict__ xlb, float* __restrict__ a_s, float* __restrict__ a_d,
        const int* __restrict__ ei, int* __restrict__ cur, int* __restrict__ col_src) {
    __shared__ __align__(16) float xs[4][132];
    __shared__ float w1s[96], b1s[32], b2s[64];
    __shared__ __align__(16) u16 hb[4][66 * HSTR];   // per-wave private slices
    __shared__ __align__(16) u16 fs[16][FSTR];       // block feat tile (16 rows x 64)

    bool isbf = probe_x_bf16(xsrc);
    int tid = threadIdx.x;
    int wave = tid >> 6, lane = tid & 63;
    int node0 = blockIdx.x * (4 * NPW);   // 16 consecutive batch-major nodes

    int m = lane & 15, q = lane >> 4;
    short8 bfr[4][3];
    #pragma unroll
    for (int nt = 0; nt < 4; ++nt)
        #pragma unroll
        for (int sh = 0; sh < 3; ++sh)
            bfr[nt][sh] = *(const short8*)&cw2r[(nt * 16 + m) * 96 + sh * 32 + q * 8];

    if (tid < 96) w1s[tid] = wbuf[S_CW1 + tid];
    if (tid < 32) b1s[tid] = wbuf[S_CB1 + tid];
    if (tid < 64) b2s[tid] = wbuf[S_CB2 + tid];
    if (tid < 8) xs[tid >> 1][(tid & 1) ? 129 : 0] = 0.f;
    if (tid < 64) {
        int w = tid >> 4, idx = tid & 15;
        *(u32*)&hb[w][2 * idx] = 0;
        *(u32*)&hb[w][65 * HSTR + 2 * idx] = 0;
    }
    __syncthreads();

    float* xsw = xs[wave];
    u16* hw = &hb[wave][0];

    int d = m, uu = q;
    float wa0 = w1s[6 * d + 0], wa1 = w1s[6 * d + 1], wa2 = w1s[6 * d + 2];
    float wb0 = w1s[6 * d + 3], wb1 = w1s[6 * d + 4], wb2 = w1s[6 * d + 5];
    float ba = b1s[2 * d], bb = b1s[2 * d + 1];
    float b2vv[4];
    #pragma unroll
    for (int nt = 0; nt < 4; ++nt) b2vv[nt] = b2s[nt * 16 + m];

    int node = node0 + wave;
    u32 plo = 0; float2 pf = {0.f, 0.f};
    if (isbf) plo = ((const u32*)xsrc)[(size_t)node * 64 + lane];
    else      pf  = ((const float2*)xsrc)[(size_t)node * 64 + lane];

    for (int j = 0; j < NPW; ++j) {
        if (isbf) {
            xsw[1 + 2 * lane] = u2f((u16)(plo & 0xFFFF));
            xsw[2 + 2 * lane] = u2f((u16)(plo >> 16));
        } else {
            xsw[1 + 2 * lane] = pf.x;
            xsw[2 + 2 * lane] = pf.y;
        }
        if (j + 1 < NPW) {
            int nxt = node + 4;
            if (isbf) plo = ((const u32*)xsrc)[(size_t)nxt * 64 + lane];
            else      pf  = ((const float2*)xsrc)[(size_t)nxt * 64 + lane];
        }

        #pragma unroll
        for (int it = 0; it < 16; ++it) {
            int u = uu + 4 * it;
            int t0 = 2 * u;
            float2 xa = *(const float2*)&xsw[t0];
            float2 xb = *(const float2*)&xsw[t0 + 2];
            float x0 = xa.x, x1 = xa.y, x2 = xb.x, x3 = xb.y;
            f32x2 A = {x0, x1}, Bv = {x1, x2}, Cv = {x2, x3};
            f32x2 va = {ba, ba}; va += wa0 * A; va += wa1 * Bv; va += wa2 * Cv;
            f32x2 vb = {bb, bb}; vb += wb0 * A; vb += wb1 * Bv; vb += wb2 * Cv;
            float ha = fmaxf(fmaxf(va.x, va.y), 0.f);
            float hb2 = fmaxf(fmaxf(vb.x, vb.y), 0.f);
            __hip_bfloat162 hp2 = __float22bfloat162_rn(make_float2(ha, hb2));
            u32 pack; __builtin_memcpy(&pack, &hp2, 4);
            *(u32*)&hw[(u + 1) * HSTR + 2 * d] = pack;
        }

        float pc0 = 0.f, pc1 = 0.f, pc2 = 0.f, pc3 = 0.f;
        #pragma unroll
        for (int mt = 0; mt < 4; ++mt) {
            const u16* hr = &hw[(mt * 16 + m) * HSTR + q * 8];
            short8 a0 = *(const short8*)&hr[0 * HSTR];
            short8 a1 = *(const short8*)&hr[1 * HSTR];
            short8 a2 = *(const short8*)&hr[2 * HSTR];
            f32x4 c0 = {0.f,0.f,0.f,0.f}, c1 = {0.f,0.f,0.f,0.f};
            f32x4 c2 = {0.f,0.f,0.f,0.f}, c3 = {0.f,0.f,0.f,0.f};
            c0 = __builtin_amdgcn_mfma_f32_16x16x32_bf16(a0, bfr[0][0], c0, 0, 0, 0);
            c1 = __builtin_amdgcn_mfma_f32_16x16x32_bf16(a0, bfr[1][0], c1, 0, 0, 0);
            c2 = __builtin_amdgcn_mfma_f32_16x16x32_bf16(a0, bfr[2][0], c2, 0, 0, 0);
            c3 = __builtin_amdgcn_mfma_f32_16x16x32_bf16(a0, bfr[3][0], c3, 0, 0, 0);
            c0 = __builtin_amdgcn_mfma_f32_16x16x32_bf16(a1, bfr[0][1], c0, 0, 0, 0);
            c1 = __builtin_amdgcn_mfma_f32_16x16x32_bf16(a1, bfr[1][1], c1, 0, 0, 0);
            c2 = __builtin_amdgcn_mfma_f32_16x16x32_bf16(a1, bfr[2][1], c2, 0, 0, 0);
            c3 = __builtin_amdgcn_mfma_f32_16x16x32_bf16(a1, bfr[3][1], c3, 0, 0, 0);
            c0 = __builtin_amdgcn_mfma_f32_16x16x32_bf16(a2, bfr[0][2], c0, 0, 0, 0);
            c1 = __builtin_amdgcn_mfma_f32_16x16x32_bf16(a2, bfr[1][2], c1, 0, 0, 0);
            c2 = __builtin_amdgcn_mfma_f32_16x16x32_bf16(a2, bfr[2][2], c2, 0, 0, 0);
            c3 = __builtin_amdgcn_mfma_f32_16x16x32_bf16(a2, bfr[3][2], c3, 0, 0, 0);
            pc0 += prelu(c0[0] + b2vv[0]) + prelu(c0[1] + b2vv[0])
                 + prelu(c0[2] + b2vv[0]) + prelu(c0[3] + b2vv[0]);
            pc1 += prelu(c1[0] + b2vv[1]) + prelu(c1[1] + b2vv[1])
                 + prelu(c1[2] + b2vv[1]) + prelu(c1[3] + b2vv[1]);
            pc2 += prelu(c2[0] + b2vv[2]) + prelu(c2[1] + b2vv[2])
                 + prelu(c2[2] + b2vv[2]) + prelu(c2[3] + b2vv[2]);
            pc3 += prelu(c3[0] + b2vv[3]) + prelu(c3[1] + b2vv[3])
                 + prelu(c3[2] + b2vv[3]) + prelu(c3[3] + b2vv[3]);
        }
        pc0 += __shfl_xor(pc0, 16, 64); pc0 += __shfl_xor(pc0, 32, 64);
        pc1 += __shfl_xor(pc1, 16, 64); pc1 += __shfl_xor(pc1, 32, 64);
        pc2 += __shfl_xor(pc2, 16, 64); pc2 += __shfl_xor(pc2, 32, 64);
        pc3 += __shfl_xor(pc3, 16, 64); pc3 += __shfl_xor(pc3, 32, 64);
        float v = (q == 0) ? pc0 : (q == 1) ? pc1 : (q == 2) ? pc2 : pc3;
        u16 fv = f2b(v * (1.f / 64.f));
        featb[(size_t)node * 64 + lane] = fv;   // batch-major, for diagnostics
        fs[wave + 4 * j][lane] = fv;            // block feat tile for fused gemm

        node += 4;
    }

    // ---- CSR fill slice (blocks < FILL_BLK), before the barrier: independent ----
    if (blockIdx.x < FILL_BLK) {
        bool ei64 = probe_ei64(ei);
        int e = blockIdx.x * 256 + tid;
        if (e < NEDGE + NNODE) {
            int src, dst;
            if (e < NEDGE) {
                if (ei64) { src = ei[2 * e]; dst = ei[2 * (NEDGE + e)]; }
                else      { src = ei[e];     dst = ei[NEDGE + e]; }
            } else {
                src = dst = e - NEDGE;
            }
            if (dst >= 0 && dst < NNODE) {
                int pos = atomicAdd(&cur[dst], 1);
                if (pos >= 0 && pos < NEDGE + NNODE) col_src[pos] = src;
            }
        }
    }

    __syncthreads();   // fs complete

    // ---- fused GAT-0 GEMM: 16 rows x 64 cols per wave (head h = wave) ----
    {
        f32x4 acc[4];
        #pragma unroll
        for (int ntl = 0; ntl < 4; ++ntl) acc[ntl] = {0.f, 0.f, 0.f, 0.f};
        #pragma unroll
        for (int kc = 0; kc < 64; kc += 32) {
            short8 a = *(const short8*)&fs[m][kc + q * 8];
            #pragma unroll
            for (int ntl = 0; ntl < 4; ++ntl) {
                int col0 = wave * 64 + ntl * 16;
                short8 bw = *(const short8*)&W0t[(size_t)(col0 + m) * 64 + kc + q * 8];
                acc[ntl] = __builtin_amdgcn_mfma_f32_16x16x32_bf16(a, bw, acc[ntl], 0, 0, 0);
            }
        }
        #pragma unroll
        for (int ntl = 0; ntl < 4; ++ntl) {
            #pragma unroll
            for (int r = 0; r < 4; ++r)
                xlb[(size_t)(node0 + q * 4 + r) * 256 + wave * 64 + ntl * 16 + m]
                    = f2b(acc[ntl][r]);
        }
        const float* asw_p = wbuf + S_AS0;
        const float* adw_p = wbuf + S_AD0;
        float sh_s[4] = {0, 0, 0, 0}, sh_d[4] = {0, 0, 0, 0};
        #pragma unroll
        for (int ntl = 0; ntl < 4; ++ntl) {
            float asw = asw_p[wave * 64 + ntl * 16 + m];
            float adw = adw_p[wave * 64 + ntl * 16 + m];
            #pragma unroll
            for (int r = 0; r < 4; ++r) {
                sh_s[r] += acc[ntl][r] * asw;
                sh_d[r] += acc[ntl][r] * adw;
            }
        }
        #pragma unroll
        for (int off = 1; off < 16; off <<= 1) {
            #pragma unroll
            for (int r = 0; r < 4; ++r) {
                sh_s[r] += __shfl_xor(sh_s[r], off, 64);
                sh_d[r] += __shfl_xor(sh_d[r], off, 64);
            }
        }
        if (m == 0) {
            int bb2 = node0 / NNODE;            // block never straddles a batch
            int nn0 = node0 - bb2 * NNODE;
            #pragma unroll
            for (int r = 0; r < 4; ++r) {
                int nn = nn0 + q * 4 + r;
                a_s[(size_t)nn * 16 + bb2 * 4 + wave] = sh_s[r];
                a_d[(size_t)nn * 16 + bb2 * 4 + wave] = sh_d[r];
            }
        }
    }
}

// ------ zero-LDS MFMA GEMM (MT=1), fused attention scores (layer 1) ------
__global__ __launch_bounds__(256) void k_gemm(const u16* __restrict__ A,
        const u16* __restrict__ Wt, const float* __restrict__ att_s_w,
        const float* __restrict__ att_d_w, u16* __restrict__ outb,
        float* __restrict__ a_s, float* __restrict__ a_d) {
    const int K = 256;
    int wave = threadIdx.x >> 6, lane = threadIdx.x & 63;
    int row0 = (blockIdx.x * 4 + wave) * 16;
    int m = lane & 15, q = lane >> 4;
    f32x4 acc[16];
    #pragma unroll
    for (int nt = 0; nt < 16; ++nt) acc[nt] = {0.f, 0.f, 0.f, 0.f};
    for (int kc = 0; kc < K; kc += 32) {
        short8 a = *(const short8*)&A[(size_t)(row0 + m) * K + kc + q * 8];
        #pragma unroll
        for (int nt = 0; nt < 16; ++nt) {
            short8 b = *(const short8*)&Wt[(size_t)(nt * 16 + m) * K + kc + q * 8];
            acc[nt] = __builtin_amdgcn_mfma_f32_16x16x32_bf16(a, b, acc[nt], 0, 0, 0);
        }
    }
    #pragma unroll
    for (int nt = 0; nt < 16; ++nt) {
        #pragma unroll
        for (int r = 0; r < 4; ++r)
            outb[(size_t)(row0 + q * 4 + r) * 256 + nt * 16 + m] = f2b(acc[nt][r]);
    }
    float sh_s[4][4] = {{0}}, sh_d[4][4] = {{0}};
    #pragma unroll
    for (int nt = 0; nt < 16; ++nt) {
        int h = nt >> 2;
        int cc = (nt & 3) * 16 + m;
        float asw = att_s_w[h * 64 + cc];
        float adw = att_d_w[h * 64 + cc];
        #pragma unroll
        for (int r = 0; r < 4; ++r) {
            sh_s[h][r] += acc[nt][r] * asw;
            sh_d[h][r] += acc[nt][r] * adw;
        }
    }
    #pragma unroll
    for (int off = 1; off < 16; off <<= 1) {
        #pragma unroll
        for (int h = 0; h < 4; ++h)
            #pragma unroll
            for (int r = 0; r < 4; ++r) {
                sh_s[h][r] += __shfl_xor(sh_s[h][r], off, 64);
                sh_d[h][r] += __shfl_xor(sh_d[h][r], off, 64);
            }
    }
    if (m == 0) {
        #pragma unroll
        for (int r = 0; r < 4; ++r) {
            int row = row0 + q * 4 + r;          // batch-major: b*NNODE + nn
            int b = row / NNODE, nn = row - b * NNODE;
            float4 vs = {sh_s[0][r], sh_s[1][r], sh_s[2][r], sh_s[3][r]};
            float4 vd = {sh_d[0][r], sh_d[1][r], sh_d[2][r], sh_d[3][r]};
            *(float4*)&a_s[(size_t)nn * 16 + b * 4] = vs;
            *(float4*)&a_d[(size_t)nn * 16 + b * 4] = vd;
        }
    }
}

// ---------------- GAT aggregation: single-pass online softmax ----------------
// a_s layout [nn*16 + b*4 + h] (4-batch line sharing); xlb/gb batch-major rows.
__global__ __launch_bounds__(256) void k_agg(const u16* __restrict__ xlb,
        const float* __restrict__ a_s, const float* __restrict__ a_d,
        const int* __restrict__ row_ptr, const int* __restrict__ col_src,
        const float* __restrict__ bias, u16* __restrict__ gb_out) {
    int wave = threadIdx.x >> 6, lane = threadIdx.x & 63;
    int dst = __builtin_amdgcn_readfirstlane(blockIdx.x * 2 + (wave >> 1));
    int bp = (wave & 1) * 2;
    int beg = __builtin_amdgcn_readfirstlane(row_ptr[dst]);
    int end = __builtin_amdgcn_readfirstlane(row_ptr[dst + 1]);

    int bl = lane >> 5;
    int s = lane & 31;
    int h = s >> 3;
    int b = bp + bl;
    int asoff = b * 4 + h;
    size_t rowb = (size_t)b * NNODE;
    float advh = a_d[(size_t)dst * 16 + asoff];

    float m = -INFINITY, l = 0.f;
    float acc[8];
    #pragma unroll
    for (int k = 0; k < 8; ++k) acc[k] = 0.f;

    int i = beg;
    int n0 = 0, n1 = 0, n2 = 0, n3 = 0;
    if (i + 4 <= end) {
        n0 = col_src[i]; n1 = col_src[i + 1];
        n2 = col_src[i + 2]; n3 = col_src[i + 3];
    }
    while (i + 4 <= end) {
        int s0 = min(max(n0, 0), NNODE - 1);
        int s1 = min(max(n1, 0), NNODE - 1);
        int s2 = min(max(n2, 0), NNODE - 1);
        int s3 = min(max(n3, 0), NNODE - 1);
        float a0 = a_s[(size_t)s0 * 16 + asoff];
        float a1 = a_s[(size_t)s1 * 16 + asoff];
        float a2 = a_s[(size_t)s2 * 16 + asoff];
        float a3 = a_s[(size_t)s3 * 16 + asoff];
        short8 x0 = *(const short8*)&xlb[(rowb + s0) * 256 + s * 8];
        short8 x1 = *(const short8*)&xlb[(rowb + s1) * 256 + s * 8];
        short8 x2 = *(const short8*)&xlb[(rowb + s2) * 256 + s * 8];
        short8 x3 = *(const short8*)&xlb[(rowb + s3) * 256 + s * 8];
        i += 4;
        if (i + 4 <= end) {   // preload next chunk's col_src
            n0 = col_src[i]; n1 = col_src[i + 1];
            n2 = col_src[i + 2]; n3 = col_src[i + 3];
        }
        float e0 = a0 + advh; e0 = (e0 >= 0.f) ? e0 : 0.2f * e0;
        float e1 = a1 + advh; e1 = (e1 >= 0.f) ? e1 : 0.2f * e1;
        float e2 = a2 + advh; e2 = (e2 >= 0.f) ? e2 : 0.2f * e2;
        float e3 = a3 + advh; e3 = (e3 >= 0.f) ? e3 : 0.2f * e3;
        float cmax = fmaxf(fmaxf(e0, e1), fmaxf(e2, e3));
        if (__any(cmax > m)) {      // wave-uniform, rare after warmup
            float mn = fmaxf(m, cmax);
            float r = __expf(m - mn);
            m = mn;
            l *= r;
            #pragma unroll
            for (int k = 0; k < 8; ++k) acc[k] *= r;
        }
        float p0 = __expf(e0 - m); l += p0;
        #pragma unroll
        for (int k = 0; k < 8; ++k) acc[k] += p0 * u2f((u16)x0[k]);
        float p1 = __expf(e1 - m); l += p1;
        #pragma unroll
        for (int k = 0; k < 8; ++k) acc[k] += p1 * u2f((u16)x1[k]);
        float p2 = __expf(e2 - m); l += p2;
        #pragma unroll
        for (int k = 0; k < 8; ++k) acc[k] += p2 * u2f((u16)x2[k]);
        float p3 = __expf(e3 - m); l += p3;
        #pragma unroll
        for (int k = 0; k < 8; ++k) acc[k] += p3 * u2f((u16)x3[k]);
    }
    for (; i < end; ++i) {
        int s0 = min(max(col_src[i], 0), NNODE - 1);
        float a0 = a_s[(size_t)s0 * 16 + asoff];
        short8 x0 = *(const short8*)&xlb[(rowb + s0) * 256 + s * 8];
        float e0 = a0 + advh; e0 = (e0 >= 0.f) ? e0 : 0.2f * e0;
        if (__any(e0 > m)) {
            float mn = fmaxf(m, e0);
            float r = __expf(m - mn);
            m = mn;
            l *= r;
            #pragma unroll
            for (int k = 0; k < 8; ++k) acc[k] *= r;
        }
        float p0 = __expf(e0 - m); l += p0;
        #pragma unroll
        for (int k = 0; k < 8; ++k) acc[k] += p0 * u2f((u16)x0[k]);
    }

    float rl = 1.f / (l + 1e-16f);
    short8 o;
    #pragma unroll
    for (int k = 0; k < 8; ++k)
        o[k] = (short)f2b(prelu(acc[k] * rl + bias[s * 8 + k]));
    *(short8*)&gb_out[(rowb + dst) * 256 + s * 8] = o;
}

// ---------------- attribution head (blocks <625) + pooled sum (blocks >=625) ----------
__global__ __launch_bounds__(256) void k_attrpool(const u16* __restrict__ gb,
        const u16* __restrict__ Wa1t, const float* __restrict__ wbuf,
        float* __restrict__ out, float* __restrict__ pooled) {
    if (blockIdx.x >= 625) {   // pool part (batch-major rows)
        int pb = blockIdx.x - 625;
        int b = pb >> 6;
        int chunk = pb & 63;
        int cch = threadIdx.x;
        int n0 = chunk * 157;
        int n1 = min(NNODE, n0 + 157);
        size_t rowb = (size_t)b * NNODE;
        float acc = 0.f;
        int n = n0;
        for (; n + 4 <= n1; n += 4) {
            float v0 = u2f(gb[(rowb + n) * 256 + cch]);
            float v1 = u2f(gb[(rowb + n + 1) * 256 + cch]);
            float v2 = u2f(gb[(rowb + n + 2) * 256 + cch]);
            float v3 = u2f(gb[(rowb + n + 3) * 256 + cch]);
            acc += v0; acc += v1; acc += v2; acc += v3;
        }
        for (; n < n1; ++n)
            acc += u2f(gb[(rowb + n) * 256 + cch]);
        atomicAdd(&pooled[b * 256 + cch], acc);
        return;
    }
    int wave = threadIdx.x >> 6, lane = threadIdx.x & 63;
    int row0 = (blockIdx.x * 4 + wave) * 16;
    int m = lane & 15, q = lane >> 4;
    f32x4 acc[4];
    #pragma unroll
    for (int nt = 0; nt < 4; ++nt) acc[nt] = {0.f, 0.f, 0.f, 0.f};
    for (int kc = 0; kc < 256; kc += 32) {
        short8 a = *(const short8*)&gb[(size_t)(row0 + m) * 256 + kc + q * 8];
        #pragma unroll
        for (int nt = 0; nt < 4; ++nt) {
            short8 b = *(const short8*)&Wa1t[(size_t)(nt * 16 + m) * 256 + kc + q * 8];
            acc[nt] = __builtin_amdgcn_mfma_f32_16x16x32_bf16(a, b, acc[nt], 0, 0, 0);
        }
    }
    float part[4] = {0, 0, 0, 0};
    #pragma unroll
    for (int nt = 0; nt < 4; ++nt) {
        int col = nt * 16 + m;
        float ba1v = wbuf[S_BA1 + col];
        float wa2v = wbuf[S_WA2 + col];
        #pragma unroll
        for (int r = 0; r < 4; ++r)
            part[r] += prelu(acc[nt][r] + ba1v) * wa2v;
    }
    #pragma unroll
    for (int off = 1; off < 16; off <<= 1) {
        #pragma unroll
        for (int r = 0; r < 4; ++r)
            part[r] += __shfl_xor(part[r], off, 64);
    }
    if (m == 0) {
        float ba2v = wbuf[S_BA2];
        #pragma unroll
        for (int r = 0; r < 4; ++r) {
            int row = row0 + q * 4 + r;          // batch-major = b*NNODE+n
            float v = part[r] + ba2v;
            out[8 + row] = 1.f / (1.f + __expf(-v));
        }
    }
}

// ---------------- classification head (blocks 0-3) + diagnostics (block 4) ----------
__global__ __launch_bounds__(128) void k_logits(const float* __restrict__ pooled,
        const float* __restrict__ wbuf, const void* __restrict__ Wc1p,
        float* __restrict__ out,
        const u16* __restrict__ featb, const u16* __restrict__ gb,
        const int* __restrict__ row_ptr, const int* __restrict__ ei,
        const void* __restrict__ xsrc, int hostbad) {
    int tid = threadIdx.x;
    bool isbf = probe_x_bf16(xsrc);
    if (blockIdx.x == 4) {   // sampled diagnostics
        __shared__ float red[128];
        bool ei64 = probe_ei64(ei);
        float mx[2] = {0.f, 0.f};
        const u16* bufs[2] = {featb, gb};
        for (int qq = 0; qq < 2; ++qq) {
            const u16* p = bufs[qq];
            float m = 0.f;
            for (int i = tid; i < 2048; i += 128) {
                float v = u2f(p[i]);
                if (v != v) m = 1e30f;
                m = fmaxf(m, fabsf(v));
            }
            red[tid] = m;
            __syncthreads();
            for (int s2 = 64; s2 > 0; s2 >>= 1) {
                if (tid < s2) red[tid] = fmaxf(red[tid], red[tid + s2]);
                __syncthreads();
            }
            mx[qq] = red[0];
            __syncthreads();
        }
        if (tid == 0) {
            int fb = (mx[0] > 1e8f || mx[0] < 1e-6f) ? 1 : 0;
            int gbad = (mx[1] > 1e8f || mx[1] < 1e-6f) ? 1 : 0;
            int cb = (row_ptr[NNODE] != NEDGE + NNODE) ? 1 : 0;
            int code = 100 * fb + 400 * gbad + 800 * cb + 6400 * hostbad;
            if (code) {
                code += 1600 * (isbf ? 0 : 1);
                code += 3200 * (ei64 ? 1 : 0);
                for (int j = 0; j < 8; ++j) out[j] = (float)code;
            }
        }
        return;
    }
    __shared__ float pm[256];
    __shared__ float red4[4];
    int b = blockIdx.x;
    pm[tid] = pooled[b * 256 + tid] * (1.f / NNODE);
    pm[tid + 128] = pooled[b * 256 + tid + 128] * (1.f / NNODE);
    __syncthreads();
    float acc = wbuf[S_BC1 + tid];
    if (isbf) {
        const u16* w = (const u16*)Wc1p;
        #pragma unroll 4
        for (int k = 0; k < 256; ++k)
            acc += pm[k] * u2f(w[k * 128 + tid]);
    } else {
        const float* w = (const float*)Wc1p;
        #pragma unroll 4
        for (int k = 0; k < 256; ++k)
            acc += pm[k] * w[k * 128 + tid];
    }
    float hv = prelu(acc);
    float p0 = hv * wbuf[S_WC2 + tid * 2];
    float p1 = hv * wbuf[S_WC2 + tid * 2 + 1];
    #pragma unroll
    for (int off = 32; off > 0; off >>= 1) {
        p0 += __shfl_xor(p0, off, 64);
        p1 += __shfl_xor(p1, off, 64);
    }
    int wv = tid >> 6, lane = tid & 63;
    if (lane == 0) { red4[wv * 2] = p0; red4[wv * 2 + 1] = p1; }
    __syncthreads();
    if (tid < 2)
        out[b * 2 + tid] = red4[tid] + red4[2 + tid] + wbuf[S_BC2 + tid];
}

extern "C" void kernel_launch(void* const* d_in, const int* in_sizes, int n_in,
                              void* d_out, int out_size, void* d_ws, size_t ws_size,
                              hipStream_t stream) {
    const void* x  = d_in[0];
    const int*  ei = (const int*)d_in[1];
    float* out = (float*)d_out;

    WPtrs wp;
    for (int j = 0; j < 20; ++j) wp.p[j] = d_in[j + 2];

    char* ws = (char*)d_ws;
    size_t off = 0;
    auto alloc = [&](size_t bytes) -> void* {
        void* p = ws + off;
        off += (bytes + 255) & ~(size_t)255;
        return p;
    };
    float* wbuf    = (float*)alloc((size_t)S_TOTAL * 4);
    u16*   featb   = (u16*)  alloc((size_t)BATCH * NNODE * 64 * 2);
    u16*   xlb     = (u16*)  alloc((size_t)BATCH * NNODE * 256 * 2);
    u16*   gb      = (u16*)  alloc((size_t)BATCH * NNODE * 256 * 2);
    float* a_s     = (float*)alloc((size_t)BATCH * NNODE * 4 * 4);
    float* a_d     = (float*)alloc((size_t)BATCH * NNODE * 4 * 4);
    u16*   cw2r    = (u16*)alloc(6144 * 2);
    u16*   W0t     = (u16*)alloc(16384 * 2);
    u16*   W1t     = (u16*)alloc(65536 * 2);
    u16*   Wa1t    = (u16*)alloc(16384 * 2);
    // counts and pooled ADJACENT: one memset zeroes both
    int*   counts  = (int*)alloc(NNODE * 4);           // padded to 40192
    float* pooled  = (float*)alloc(BATCH * 256 * 4);   // 4096
    int*   row_ptr = (int*)alloc((NNODE + 1) * 4);
    int*   cur     = (int*)alloc(NNODE * 4);
    int*   col_src = (int*)alloc((NEDGE + NNODE) * 4);
    (void)ws_size; (void)out_size;

    int hostbad = (n_in != 22 || in_sizes[0] != BATCH * NNODE * TLEN ||
                   in_sizes[1] != 2 * NEDGE) ? 1 : 0;

    hipMemsetAsync(counts, 0, 40192 + 4096, stream);

    k_pre<<<PRE_TBLK + 9, 256, 0, stream>>>(wp, x, ei, wbuf, cw2r, W0t, W1t, Wa1t, counts);
    k_scan<<<1, 1024, 0, stream>>>(counts, cur, row_ptr);

    // fused conv + GAT-0 gemm + CSR fill (16 nodes/block, solo-wave conv)
    k_conv<<<BATCH * NNODE / 16, 256, 0, stream>>>(x, wbuf, cw2r, W0t, featb,
            xlb, a_s, a_d, ei, cur, col_src);

    // GAT layer 0 aggregation
    k_agg<<<NNODE / 2, 256, 0, stream>>>(xlb, a_s, a_d, row_ptr, col_src, wbuf + S_B0, gb);

    // GAT layer 1
    k_gemm<<<BATCH * NNODE / 64, 256, 0, stream>>>(gb, W1t,
            wbuf + S_AS1, wbuf + S_AD1, xlb, a_s, a_d);
    k_agg<<<NNODE / 2, 256, 0, stream>>>(xlb, a_s, a_d, row_ptr, col_src, wbuf + S_B1, gb);

    // heads
    k_attrpool<<<625 + 256, 256, 0, stream>>>(gb, Wa1t, wbuf, out, pooled);
    k_logits<<<5, 128, 0, stream>>>(pooled, wbuf, wp.p[12], out, featb, gb, row_ptr, ei, x, hostbad);
}

// Round 9
// 358.930 us; speedup vs baseline: 1.1208x; 1.0857x over previous
//
#include <hip/hip_runtime.h>
#include <hip/hip_bf16.h>
#include <math.h>

typedef __hip_bfloat16 bf16;
typedef unsigned short u16;
typedef unsigned int u32;
typedef __attribute__((ext_vector_type(8))) short short8;
typedef __attribute__((ext_vector_type(4))) float f32x4;
typedef __attribute__((ext_vector_type(2))) float f32x2;

#define BATCH 4
#define NNODE 10000
#define TLEN 128
#define NEDGE 160000
#define GDIM 256
#define NHEAD 4

// small-weight fp32 staging offsets (everything except W0/W1/Wa1/Wc1)
#define S_CW1 0
#define S_CB1 96
#define S_CB2 128
#define S_AS0 192
#define S_AD0 448
#define S_B0  704
#define S_AS1 960
#define S_AD1 1216
#define S_B1  1472
#define S_BC1 1728
#define S_WC2 1856
#define S_BC2 2112
#define S_BA1 2114
#define S_WA2 2178
#define S_BA2 2242
#define S_TOTAL 2243

__device__ __forceinline__ float prelu(float v) { return fmaxf(v, 0.f); }
__device__ __forceinline__ u16 f2b(float f) {
    union { float f; u32 u; } v; v.f = f;
    u32 r = v.u + 0x7FFF + ((v.u >> 16) & 1);
    return (u16)(r >> 16);
}
__device__ __forceinline__ float u2f(u16 u) {
    union { u32 u; float f; } v; v.u = ((u32)u) << 16;
    return v.f;
}
__device__ __forceinline__ float ldw(const void* p, int off, bool isbf) {
    return isbf ? u2f(((const u16*)p)[off]) : ((const float*)p)[off];
}

// per-wave inline dtype probes (all waves compute identical results)
__device__ __forceinline__ bool probe_x_bf16(const void* xsrc) {
    int lane = threadIdx.x & 63;
    u16 h = ((const u16*)xsrc)[2 * lane];
    int e = (h >> 7) & 0xFF;
    unsigned long long m = __ballot(e >= 117 && e <= 130);
    return __popcll(m) >= 32;
}
__device__ __forceinline__ bool probe_ei64(const int* ei) {
    int lane = threadIdx.x & 63;
    int v = ei[2 * lane + 1];
    unsigned long long m = __ballot(v == 0);
    return __popcll(m) >= 56;
}

struct WPtrs { const void* p[20]; };

// ------ merged: bf16 transposes + dst histogram + small-weight fp32 staging ------
#define PRE_TBLK 665   // covers max(65536, 170000) indices
__global__ __launch_bounds__(256) void k_pre(WPtrs wp, const void* __restrict__ xsrc,
        const int* __restrict__ ei, float* __restrict__ wbuf,
        u16* __restrict__ cw2r, u16* __restrict__ W0t, u16* __restrict__ W1t,
        u16* __restrict__ Wa1t, int* __restrict__ counts) {
    bool isbf = probe_x_bf16(xsrc);
    int b = blockIdx.x;
    if (b >= PRE_TBLK) {   // small-weight staging (9 blocks)
        const int C2[16] = {0,96,128,192,448,704,960,1216,1472,1728,1856,2112,
                            2114,2178,2242,2243};
        const int SRC[15] = {0,1,3,5,6,7,9,10,11,13,14,15,17,18,19};
        int i = (b - PRE_TBLK) * 256 + threadIdx.x;
        if (i >= S_TOTAL) return;
        int j = 14;
        for (int t = 0; t < 15; ++t) { if (i < C2[t + 1]) { j = t; break; } }
        wbuf[i] = ldw(wp.p[SRC[j]], i - C2[j], isbf);
        return;
    }
    int i = b * 256 + threadIdx.x;
    if (i < 6144) {   // cw2r[c2][k'=dk*32+ci]
        int c2 = i / 96, k = i - c2 * 96, s = k >> 5, ci = k & 31;
        cw2r[i] = f2b(ldw(wp.p[2], c2 * 96 + ci * 3 + s, isbf));
    }
    if (i < 16384) {  // W0t / Wa1t, coalesced reads
        int k = i >> 8, c = i & 255;
        W0t[c * 64 + k] = f2b(ldw(wp.p[4], k * 256 + c, isbf));
        int ka = i >> 6, ca = i & 63;
        Wa1t[ca * 256 + ka] = f2b(ldw(wp.p[16], ka * 64 + ca, isbf));
    }
    if (i < 65536) {  // W1t
        int k = i >> 8, c = i & 255;
        W1t[c * 256 + k] = f2b(ldw(wp.p[8], k * 256 + c, isbf));
    }
    if (i < NEDGE + NNODE) {   // dst histogram (counts pre-zeroed by memset)
        bool ei64 = probe_ei64(ei);
        int dst;
        if (i < NEDGE) dst = ei64 ? ei[2 * (NEDGE + i)] : ei[NEDGE + i];
        else dst = i - NEDGE;
        if (dst >= 0 && dst < NNODE) atomicAdd(&counts[dst], 1);
    }
}

// ---------------- single-block scan ----------------
__global__ __launch_bounds__(1024) void k_scan(const int* __restrict__ counts,
        int* __restrict__ cur, int* __restrict__ row_ptr) {
    __shared__ int buf[1024];
    int t = threadIdx.x;
    int base = t * 10;
    int c[10];
    int s = 0;
    #pragma unroll
    for (int i = 0; i < 10; ++i) {
        int idx = base + i;
        c[i] = (idx < NNODE) ? counts[idx] : 0;
        s += c[i];
    }
    buf[t] = s;
    __syncthreads();
    for (int off = 1; off < 1024; off <<= 1) {
        int v = (t >= off) ? buf[t - off] : 0;
        __syncthreads();
        buf[t] += v;
        __syncthreads();
    }
    int run = buf[t] - s;   // exclusive prefix of this thread's chunk
    #pragma unroll
    for (int i = 0; i < 10; ++i) {
        int idx = base + i;
        if (idx < NNODE) {
            cur[idx] = run;
            run += c[i];
            row_ptr[idx + 1] = run;
        }
    }
    if (t == 0) row_ptr[0] = 0;
}

// ---- fused temporal conv + GAT-0 GEMM + CSR fill (R8 structure) ----
#define HSTR 40
#define FSTR 72
#define NPW 4
#define FILL_BLK 665
__global__ __launch_bounds__(256) void k_conv(const void* __restrict__ xsrc,
        const float* __restrict__ wbuf, const u16* __restrict__ cw2r,
        const u16* __restrict__ W0t, u16* __restrict__ featb,
        u16* __restrict__ xlb, float* __restrict__ a_s, float* __restrict__ a_d,
        const int* __restrict__ ei, int* __restrict__ cur, int* __restrict__ col_src) {
    __shared__ __align__(16) float xs[4][132];
    __shared__ float w1s[96], b1s[32], b2s[64];
    __shared__ __align__(16) u16 hb[4][66 * HSTR];   // per-wave private slices
    __shared__ __align__(16) u16 fs[16][FSTR];       // block feat tile (16 rows x 64)

    bool isbf = probe_x_bf16(xsrc);
    int tid = threadIdx.x;
    int wave = tid >> 6, lane = tid & 63;
    int node0 = blockIdx.x * (4 * NPW);   // 16 consecutive batch-major nodes

    int m = lane & 15, q = lane >> 4;
    short8 bfr[4][3];
    #pragma unroll
    for (int nt = 0; nt < 4; ++nt)
        #pragma unroll
        for (int sh = 0; sh < 3; ++sh)
            bfr[nt][sh] = *(const short8*)&cw2r[(nt * 16 + m) * 96 + sh * 32 + q * 8];

    if (tid < 96) w1s[tid] = wbuf[S_CW1 + tid];
    if (tid < 32) b1s[tid] = wbuf[S_CB1 + tid];
    if (tid < 64) b2s[tid] = wbuf[S_CB2 + tid];
    if (tid < 8) xs[tid >> 1][(tid & 1) ? 129 : 0] = 0.f;
    if (tid < 64) {
        int w = tid >> 4, idx = tid & 15;
        *(u32*)&hb[w][2 * idx] = 0;
        *(u32*)&hb[w][65 * HSTR + 2 * idx] = 0;
    }
    __syncthreads();

    float* xsw = xs[wave];
    u16* hw = &hb[wave][0];

    int d = m, uu = q;
    float wa0 = w1s[6 * d + 0], wa1 = w1s[6 * d + 1], wa2 = w1s[6 * d + 2];
    float wb0 = w1s[6 * d + 3], wb1 = w1s[6 * d + 4], wb2 = w1s[6 * d + 5];
    float ba = b1s[2 * d], bb = b1s[2 * d + 1];
    float b2vv[4];
    #pragma unroll
    for (int nt = 0; nt < 4; ++nt) b2vv[nt] = b2s[nt * 16 + m];

    int node = node0 + wave;
    u32 plo = 0; float2 pf = {0.f, 0.f};
    if (isbf) plo = ((const u32*)xsrc)[(size_t)node * 64 + lane];
    else      pf  = ((const float2*)xsrc)[(size_t)node * 64 + lane];

    for (int j = 0; j < NPW; ++j) {
        if (isbf) {
            xsw[1 + 2 * lane] = u2f((u16)(plo & 0xFFFF));
            xsw[2 + 2 * lane] = u2f((u16)(plo >> 16));
        } else {
            xsw[1 + 2 * lane] = pf.x;
            xsw[2 + 2 * lane] = pf.y;
        }
        if (j + 1 < NPW) {
            int nxt = node + 4;
            if (isbf) plo = ((const u32*)xsrc)[(size_t)nxt * 64 + lane];
            else      pf  = ((const float2*)xsrc)[(size_t)nxt * 64 + lane];
        }

        #pragma unroll
        for (int it = 0; it < 16; ++it) {
            int u = uu + 4 * it;
            int t0 = 2 * u;
            float2 xa = *(const float2*)&xsw[t0];
            float2 xb = *(const float2*)&xsw[t0 + 2];
            float x0 = xa.x, x1 = xa.y, x2 = xb.x, x3 = xb.y;
            f32x2 A = {x0, x1}, Bv = {x1, x2}, Cv = {x2, x3};
            f32x2 va = {ba, ba}; va += wa0 * A; va += wa1 * Bv; va += wa2 * Cv;
            f32x2 vb = {bb, bb}; vb += wb0 * A; vb += wb1 * Bv; vb += wb2 * Cv;
            float ha = fmaxf(fmaxf(va.x, va.y), 0.f);
            float hb2 = fmaxf(fmaxf(vb.x, vb.y), 0.f);
            __hip_bfloat162 hp2 = __float22bfloat162_rn(make_float2(ha, hb2));
            u32 pack; __builtin_memcpy(&pack, &hp2, 4);
            *(u32*)&hw[(u + 1) * HSTR + 2 * d] = pack;
        }

        float pc0 = 0.f, pc1 = 0.f, pc2 = 0.f, pc3 = 0.f;
        #pragma unroll
        for (int mt = 0; mt < 4; ++mt) {
            const u16* hr = &hw[(mt * 16 + m) * HSTR + q * 8];
            short8 a0 = *(const short8*)&hr[0 * HSTR];
            short8 a1 = *(const short8*)&hr[1 * HSTR];
            short8 a2 = *(const short8*)&hr[2 * HSTR];
            f32x4 c0 = {0.f,0.f,0.f,0.f}, c1 = {0.f,0.f,0.f,0.f};
            f32x4 c2 = {0.f,0.f,0.f,0.f}, c3 = {0.f,0.f,0.f,0.f};
            c0 = __builtin_amdgcn_mfma_f32_16x16x32_bf16(a0, bfr[0][0], c0, 0, 0, 0);
            c1 = __builtin_amdgcn_mfma_f32_16x16x32_bf16(a0, bfr[1][0], c1, 0, 0, 0);
            c2 = __builtin_amdgcn_mfma_f32_16x16x32_bf16(a0, bfr[2][0], c2, 0, 0, 0);
            c3 = __builtin_amdgcn_mfma_f32_16x16x32_bf16(a0, bfr[3][0], c3, 0, 0, 0);
            c0 = __builtin_amdgcn_mfma_f32_16x16x32_bf16(a1, bfr[0][1], c0, 0, 0, 0);
            c1 = __builtin_amdgcn_mfma_f32_16x16x32_bf16(a1, bfr[1][1], c1, 0, 0, 0);
            c2 = __builtin_amdgcn_mfma_f32_16x16x32_bf16(a1, bfr[2][1], c2, 0, 0, 0);
            c3 = __builtin_amdgcn_mfma_f32_16x16x32_bf16(a1, bfr[3][1], c3, 0, 0, 0);
            c0 = __builtin_amdgcn_mfma_f32_16x16x32_bf16(a2, bfr[0][2], c0, 0, 0, 0);
            c1 = __builtin_amdgcn_mfma_f32_16x16x32_bf16(a2, bfr[1][2], c1, 0, 0, 0);
            c2 = __builtin_amdgcn_mfma_f32_16x16x32_bf16(a2, bfr[2][2], c2, 0, 0, 0);
            c3 = __builtin_amdgcn_mfma_f32_16x16x32_bf16(a2, bfr[3][2], c3, 0, 0, 0);
            pc0 += prelu(c0[0] + b2vv[0]) + prelu(c0[1] + b2vv[0])
                 + prelu(c0[2] + b2vv[0]) + prelu(c0[3] + b2vv[0]);
            pc1 += prelu(c1[0] + b2vv[1]) + prelu(c1[1] + b2vv[1])
                 + prelu(c1[2] + b2vv[1]) + prelu(c1[3] + b2vv[1]);
            pc2 += prelu(c2[0] + b2vv[2]) + prelu(c2[1] + b2vv[2])
                 + prelu(c2[2] + b2vv[2]) + prelu(c2[3] + b2vv[2]);
            pc3 += prelu(c3[0] + b2vv[3]) + prelu(c3[1] + b2vv[3])
                 + prelu(c3[2] + b2vv[3]) + prelu(c3[3] + b2vv[3]);
        }
        pc0 += __shfl_xor(pc0, 16, 64); pc0 += __shfl_xor(pc0, 32, 64);
        pc1 += __shfl_xor(pc1, 16, 64); pc1 += __shfl_xor(pc1, 32, 64);
        pc2 += __shfl_xor(pc2, 16, 64); pc2 += __shfl_xor(pc2, 32, 64);
        pc3 += __shfl_xor(pc3, 16, 64); pc3 += __shfl_xor(pc3, 32, 64);
        float v = (q == 0) ? pc0 : (q == 1) ? pc1 : (q == 2) ? pc2 : pc3;
        u16 fv = f2b(v * (1.f / 64.f));
        if (node < 32) featb[(size_t)node * 64 + lane] = fv;   // diagnostics only
        fs[wave + 4 * j][lane] = fv;            // block feat tile for fused gemm

        node += 4;
    }

    // ---- CSR fill slice (blocks < FILL_BLK), before the barrier: independent ----
    if (blockIdx.x < FILL_BLK) {
        bool ei64 = probe_ei64(ei);
        int e = blockIdx.x * 256 + tid;
        if (e < NEDGE + NNODE) {
            int src, dst;
            if (e < NEDGE) {
                if (ei64) { src = ei[2 * e]; dst = ei[2 * (NEDGE + e)]; }
                else      { src = ei[e];     dst = ei[NEDGE + e]; }
            } else {
                src = dst = e - NEDGE;
            }
            if (dst >= 0 && dst < NNODE) {
                int pos = atomicAdd(&cur[dst], 1);
                if (pos >= 0 && pos < NEDGE + NNODE) col_src[pos] = src;
            }
        }
    }

    __syncthreads();   // fs complete

    // ---- fused GAT-0 GEMM: 16 rows x 64 cols per wave (head h = wave) ----
    {
        f32x4 acc[4];
        #pragma unroll
        for (int ntl = 0; ntl < 4; ++ntl) acc[ntl] = {0.f, 0.f, 0.f, 0.f};
        #pragma unroll
        for (int kc = 0; kc < 64; kc += 32) {
            short8 a = *(const short8*)&fs[m][kc + q * 8];
            #pragma unroll
            for (int ntl = 0; ntl < 4; ++ntl) {
                int col0 = wave * 64 + ntl * 16;
                short8 bw = *(const short8*)&W0t[(size_t)(col0 + m) * 64 + kc + q * 8];
                acc[ntl] = __builtin_amdgcn_mfma_f32_16x16x32_bf16(a, bw, acc[ntl], 0, 0, 0);
            }
        }
        #pragma unroll
        for (int ntl = 0; ntl < 4; ++ntl) {
            #pragma unroll
            for (int r = 0; r < 4; ++r)
                xlb[(size_t)(node0 + q * 4 + r) * 256 + wave * 64 + ntl * 16 + m]
                    = f2b(acc[ntl][r]);
        }
        const float* asw_p = wbuf + S_AS0;
        const float* adw_p = wbuf + S_AD0;
        float sh_s[4] = {0, 0, 0, 0}, sh_d[4] = {0, 0, 0, 0};
        #pragma unroll
        for (int ntl = 0; ntl < 4; ++ntl) {
            float asw = asw_p[wave * 64 + ntl * 16 + m];
            float adw = adw_p[wave * 64 + ntl * 16 + m];
            #pragma unroll
            for (int r = 0; r < 4; ++r) {
                sh_s[r] += acc[ntl][r] * asw;
                sh_d[r] += acc[ntl][r] * adw;
            }
        }
        #pragma unroll
        for (int off = 1; off < 16; off <<= 1) {
            #pragma unroll
            for (int r = 0; r < 4; ++r) {
                sh_s[r] += __shfl_xor(sh_s[r], off, 64);
                sh_d[r] += __shfl_xor(sh_d[r], off, 64);
            }
        }
        if (m == 0) {
            int bb2 = node0 / NNODE;            // block never straddles a batch
            int nn0 = node0 - bb2 * NNODE;
            #pragma unroll
            for (int r = 0; r < 4; ++r) {
                int nn = nn0 + q * 4 + r;
                a_s[(size_t)nn * 16 + bb2 * 4 + wave] = sh_s[r];
                a_d[(size_t)nn * 16 + bb2 * 4 + wave] = sh_d[r];
            }
        }
    }
}

// ---- FUSED layer-0 aggregation + layer-1 GEMM + layer-1 attention scores ----
// 8 waves: wave w aggregates (dst = blk*4 + (w>>1), batches (w&1)*2..+2) exactly
// as k_agg, writes its bf16 row into LDS gt[16][264] (4 dsts x 4 batches = one
// 16-row M-tile). Barrier. Each wave GEMMs cols [w*32, w*32+32) over K=256 from
// gt (A) and W1t (B, L2-resident), writes C to outb and layer-1 a_s/a_d.
#define GSTR 264
__global__ __launch_bounds__(512) void k_agg_gemm(const u16* __restrict__ xlb,
        const float* __restrict__ a_s, const float* __restrict__ a_d,
        const int* __restrict__ row_ptr, const int* __restrict__ col_src,
        const float* __restrict__ bias, const u16* __restrict__ W1t,
        const float* __restrict__ wbuf, u16* __restrict__ outb,
        float* __restrict__ as_out, float* __restrict__ ad_out) {
    __shared__ __align__(16) u16 gt[16][GSTR];
    __shared__ float ps_s[8][16], ps_d[8][16];

    int tid = threadIdx.x;
    int wave = tid >> 6, lane = tid & 63;
    int dl = wave >> 1;
    int dst = __builtin_amdgcn_readfirstlane(blockIdx.x * 4 + dl);
    int bp = (wave & 1) * 2;
    int beg = __builtin_amdgcn_readfirstlane(row_ptr[dst]);
    int end = __builtin_amdgcn_readfirstlane(row_ptr[dst + 1]);

    int bl = lane >> 5;
    int s = lane & 31;
    int h = s >> 3;
    int b = bp + bl;
    int asoff = b * 4 + h;
    size_t rowb = (size_t)b * NNODE;
    float advh = a_d[(size_t)dst * 16 + asoff];

    float m = -INFINITY, l = 0.f;
    float acc[8];
    #pragma unroll
    for (int k = 0; k < 8; ++k) acc[k] = 0.f;

    int i = beg;
    int n0 = 0, n1 = 0, n2 = 0, n3 = 0;
    if (i + 4 <= end) {
        n0 = col_src[i]; n1 = col_src[i + 1];
        n2 = col_src[i + 2]; n3 = col_src[i + 3];
    }
    while (i + 4 <= end) {
        int s0 = min(max(n0, 0), NNODE - 1);
        int s1 = min(max(n1, 0), NNODE - 1);
        int s2 = min(max(n2, 0), NNODE - 1);
        int s3 = min(max(n3, 0), NNODE - 1);
        float a0 = a_s[(size_t)s0 * 16 + asoff];
        float a1 = a_s[(size_t)s1 * 16 + asoff];
        float a2 = a_s[(size_t)s2 * 16 + asoff];
        float a3 = a_s[(size_t)s3 * 16 + asoff];
        short8 x0 = *(const short8*)&xlb[(rowb + s0) * 256 + s * 8];
        short8 x1 = *(const short8*)&xlb[(rowb + s1) * 256 + s * 8];
        short8 x2 = *(const short8*)&xlb[(rowb + s2) * 256 + s * 8];
        short8 x3 = *(const short8*)&xlb[(rowb + s3) * 256 + s * 8];
        i += 4;
        if (i + 4 <= end) {
            n0 = col_src[i]; n1 = col_src[i + 1];
            n2 = col_src[i + 2]; n3 = col_src[i + 3];
        }
        float e0 = a0 + advh; e0 = (e0 >= 0.f) ? e0 : 0.2f * e0;
        float e1 = a1 + advh; e1 = (e1 >= 0.f) ? e1 : 0.2f * e1;
        float e2 = a2 + advh; e2 = (e2 >= 0.f) ? e2 : 0.2f * e2;
        float e3 = a3 + advh; e3 = (e3 >= 0.f) ? e3 : 0.2f * e3;
        float cmax = fmaxf(fmaxf(e0, e1), fmaxf(e2, e3));
        if (__any(cmax > m)) {
            float mn = fmaxf(m, cmax);
            float r = __expf(m - mn);
            m = mn;
            l *= r;
            #pragma unroll
            for (int k = 0; k < 8; ++k) acc[k] *= r;
        }
        float p0 = __expf(e0 - m); l += p0;
        #pragma unroll
        for (int k = 0; k < 8; ++k) acc[k] += p0 * u2f((u16)x0[k]);
        float p1 = __expf(e1 - m); l += p1;
        #pragma unroll
        for (int k = 0; k < 8; ++k) acc[k] += p1 * u2f((u16)x1[k]);
        float p2 = __expf(e2 - m); l += p2;
        #pragma unroll
        for (int k = 0; k < 8; ++k) acc[k] += p2 * u2f((u16)x2[k]);
        float p3 = __expf(e3 - m); l += p3;
        #pragma unroll
        for (int k = 0; k < 8; ++k) acc[k] += p3 * u2f((u16)x3[k]);
    }
    for (; i < end; ++i) {
        int s0 = min(max(col_src[i], 0), NNODE - 1);
        float a0 = a_s[(size_t)s0 * 16 + asoff];
        short8 x0 = *(const short8*)&xlb[(rowb + s0) * 256 + s * 8];
        float e0 = a0 + advh; e0 = (e0 >= 0.f) ? e0 : 0.2f * e0;
        if (__any(e0 > m)) {
            float mn = fmaxf(m, e0);
            float r = __expf(m - mn);
            m = mn;
            l *= r;
            #pragma unroll
            for (int k = 0; k < 8; ++k) acc[k] *= r;
        }
        float p0 = __expf(e0 - m); l += p0;
        #pragma unroll
        for (int k = 0; k < 8; ++k) acc[k] += p0 * u2f((u16)x0[k]);
    }

    float rl = 1.f / (l + 1e-16f);
    short8 o;
    #pragma unroll
    for (int k = 0; k < 8; ++k)
        o[k] = (short)f2b(prelu(acc[k] * rl + bias[s * 8 + k]));
    int grow = dl * 4 + b;
    *(short8*)&gt[grow][s * 8] = o;
    __syncthreads();   // gt tile complete

    // ---- GEMM: wave w computes cols [w*32, w*32+32) over all 16 rows ----
    int mm = lane & 15, q = lane >> 4;
    f32x4 ac2[2];
    ac2[0] = {0.f, 0.f, 0.f, 0.f};
    ac2[1] = {0.f, 0.f, 0.f, 0.f};
    for (int kc = 0; kc < 256; kc += 32) {
        short8 a = *(const short8*)&gt[mm][kc + q * 8];
        #pragma unroll
        for (int ntl = 0; ntl < 2; ++ntl) {
            short8 bw = *(const short8*)&W1t[(size_t)(wave * 32 + ntl * 16 + mm) * 256 + kc + q * 8];
            ac2[ntl] = __builtin_amdgcn_mfma_f32_16x16x32_bf16(a, bw, ac2[ntl], 0, 0, 0);
        }
    }
    int dbase = blockIdx.x * 4;
    // C rows: tile row = q*4+r -> (dl = q, b = r) -> global row = r*NNODE + dbase + q
    #pragma unroll
    for (int ntl = 0; ntl < 2; ++ntl) {
        #pragma unroll
        for (int r = 0; r < 4; ++r)
            outb[((size_t)r * NNODE + dbase + q) * 256 + wave * 32 + ntl * 16 + mm]
                = f2b(ac2[ntl][r]);
    }
    // layer-1 attention partials (wave covers half a head: head = wave>>1)
    float sh_s[4] = {0, 0, 0, 0}, sh_d[4] = {0, 0, 0, 0};
    #pragma unroll
    for (int ntl = 0; ntl < 2; ++ntl) {
        int col = wave * 32 + ntl * 16 + mm;
        float asw = wbuf[S_AS1 + col];
        float adw = wbuf[S_AD1 + col];
        #pragma unroll
        for (int r = 0; r < 4; ++r) {
            sh_s[r] += ac2[ntl][r] * asw;
            sh_d[r] += ac2[ntl][r] * adw;
        }
    }
    #pragma unroll
    for (int off = 1; off < 16; off <<= 1) {
        #pragma unroll
        for (int r = 0; r < 4; ++r) {
            sh_s[r] += __shfl_xor(sh_s[r], off, 64);
            sh_d[r] += __shfl_xor(sh_d[r], off, 64);
        }
    }
    if (mm == 0) {
        #pragma unroll
        for (int r = 0; r < 4; ++r) {
            ps_s[wave][q * 4 + r] = sh_s[r];
            ps_d[wave][q * 4 + r] = sh_d[r];
        }
    }
    __syncthreads();
    if (tid < 128) {   // combine the two 32-col halves of each head
        int sd = tid >> 6, hh = (tid >> 4) & 3, row2 = tid & 15;
        int nn = dbase + (row2 >> 2), bb = row2 & 3;
        if (sd == 0)
            as_out[(size_t)nn * 16 + bb * 4 + hh] = ps_s[2 * hh][row2] + ps_s[2 * hh + 1][row2];
        else
            ad_out[(size_t)nn * 16 + bb * 4 + hh] = ps_d[2 * hh][row2] + ps_d[2 * hh + 1][row2];
    }
}

// ---------------- GAT aggregation (layer 1): single-pass online softmax ----------------
__global__ __launch_bounds__(256) void k_agg(const u16* __restrict__ xlb,
        const float* __restrict__ a_s, const float* __restrict__ a_d,
        const int* __restrict__ row_ptr, const int* __restrict__ col_src,
        const float* __restrict__ bias, u16* __restrict__ gb_out) {
    int wave = threadIdx.x >> 6, lane = threadIdx.x & 63;
    int dst = __builtin_amdgcn_readfirstlane(blockIdx.x * 2 + (wave >> 1));
    int bp = (wave & 1) * 2;
    int beg = __builtin_amdgcn_readfirstlane(row_ptr[dst]);
    int end = __builtin_amdgcn_readfirstlane(row_ptr[dst + 1]);

    int bl = lane >> 5;
    int s = lane & 31;
    int h = s >> 3;
    int b = bp + bl;
    int asoff = b * 4 + h;
    size_t rowb = (size_t)b * NNODE;
    float advh = a_d[(size_t)dst * 16 + asoff];

    float m = -INFINITY, l = 0.f;
    float acc[8];
    #pragma unroll
    for (int k = 0; k < 8; ++k) acc[k] = 0.f;

    int i = beg;
    int n0 = 0, n1 = 0, n2 = 0, n3 = 0;
    if (i + 4 <= end) {
        n0 = col_src[i]; n1 = col_src[i + 1];
        n2 = col_src[i + 2]; n3 = col_src[i + 3];
    }
    while (i + 4 <= end) {
        int s0 = min(max(n0, 0), NNODE - 1);
        int s1 = min(max(n1, 0), NNODE - 1);
        int s2 = min(max(n2, 0), NNODE - 1);
        int s3 = min(max(n3, 0), NNODE - 1);
        float a0 = a_s[(size_t)s0 * 16 + asoff];
        float a1 = a_s[(size_t)s1 * 16 + asoff];
        float a2 = a_s[(size_t)s2 * 16 + asoff];
        float a3 = a_s[(size_t)s3 * 16 + asoff];
        short8 x0 = *(const short8*)&xlb[(rowb + s0) * 256 + s * 8];
        short8 x1 = *(const short8*)&xlb[(rowb + s1) * 256 + s * 8];
        short8 x2 = *(const short8*)&xlb[(rowb + s2) * 256 + s * 8];
        short8 x3 = *(const short8*)&xlb[(rowb + s3) * 256 + s * 8];
        i += 4;
        if (i + 4 <= end) {
            n0 = col_src[i]; n1 = col_src[i + 1];
            n2 = col_src[i + 2]; n3 = col_src[i + 3];
        }
        float e0 = a0 + advh; e0 = (e0 >= 0.f) ? e0 : 0.2f * e0;
        float e1 = a1 + advh; e1 = (e1 >= 0.f) ? e1 : 0.2f * e1;
        float e2 = a2 + advh; e2 = (e2 >= 0.f) ? e2 : 0.2f * e2;
        float e3 = a3 + advh; e3 = (e3 >= 0.f) ? e3 : 0.2f * e3;
        float cmax = fmaxf(fmaxf(e0, e1), fmaxf(e2, e3));
        if (__any(cmax > m)) {
            float mn = fmaxf(m, cmax);
            float r = __expf(m - mn);
            m = mn;
            l *= r;
            #pragma unroll
            for (int k = 0; k < 8; ++k) acc[k] *= r;
        }
        float p0 = __expf(e0 - m); l += p0;
        #pragma unroll
        for (int k = 0; k < 8; ++k) acc[k] += p0 * u2f((u16)x0[k]);
        float p1 = __expf(e1 - m); l += p1;
        #pragma unroll
        for (int k = 0; k < 8; ++k) acc[k] += p1 * u2f((u16)x1[k]);
        float p2 = __expf(e2 - m); l += p2;
        #pragma unroll
        for (int k = 0; k < 8; ++k) acc[k] += p2 * u2f((u16)x2[k]);
        float p3 = __expf(e3 - m); l += p3;
        #pragma unroll
        for (int k = 0; k < 8; ++k) acc[k] += p3 * u2f((u16)x3[k]);
    }
    for (; i < end; ++i) {
        int s0 = min(max(col_src[i], 0), NNODE - 1);
        float a0 = a_s[(size_t)s0 * 16 + asoff];
        short8 x0 = *(const short8*)&xlb[(rowb + s0) * 256 + s * 8];
        float e0 = a0 + advh; e0 = (e0 >= 0.f) ? e0 : 0.2f * e0;
        if (__any(e0 > m)) {
            float mn = fmaxf(m, e0);
            float r = __expf(m - mn);
            m = mn;
            l *= r;
            #pragma unroll
            for (int k = 0; k < 8; ++k) acc[k] *= r;
        }
        float p0 = __expf(e0 - m); l += p0;
        #pragma unroll
        for (int k = 0; k < 8; ++k) acc[k] += p0 * u2f((u16)x0[k]);
    }

    float rl = 1.f / (l + 1e-16f);
    short8 o;
    #pragma unroll
    for (int k = 0; k < 8; ++k)
        o[k] = (short)f2b(prelu(acc[k] * rl + bias[s * 8 + k]));
    *(short8*)&gb_out[(rowb + dst) * 256 + s * 8] = o;
}

// ---------------- attribution head (blocks <625) + pooled sum (blocks >=625) ----------
__global__ __launch_bounds__(256) void k_attrpool(const u16* __restrict__ gb,
        const u16* __restrict__ Wa1t, const float* __restrict__ wbuf,
        float* __restrict__ out, float* __restrict__ pooled) {
    if (blockIdx.x >= 625) {   // pool part (batch-major rows)
        int pb = blockIdx.x - 625;
        int b = pb >> 6;
        int chunk = pb & 63;
        int cch = threadIdx.x;
        int n0 = chunk * 157;
        int n1 = min(NNODE, n0 + 157);
        size_t rowb = (size_t)b * NNODE;
        float acc = 0.f;
        int n = n0;
        for (; n + 4 <= n1; n += 4) {
            float v0 = u2f(gb[(rowb + n) * 256 + cch]);
            float v1 = u2f(gb[(rowb + n + 1) * 256 + cch]);
            float v2 = u2f(gb[(rowb + n + 2) * 256 + cch]);
            float v3 = u2f(gb[(rowb + n + 3) * 256 + cch]);
            acc += v0; acc += v1; acc += v2; acc += v3;
        }
        for (; n < n1; ++n)
            acc += u2f(gb[(rowb + n) * 256 + cch]);
        atomicAdd(&pooled[b * 256 + cch], acc);
        return;
    }
    int wave = threadIdx.x >> 6, lane = threadIdx.x & 63;
    int row0 = (blockIdx.x * 4 + wave) * 16;
    int m = lane & 15, q = lane >> 4;
    f32x4 acc[4];
    #pragma unroll
    for (int nt = 0; nt < 4; ++nt) acc[nt] = {0.f, 0.f, 0.f, 0.f};
    for (int kc = 0; kc < 256; kc += 32) {
        short8 a = *(const short8*)&gb[(size_t)(row0 + m) * 256 + kc + q * 8];
        #pragma unroll
        for (int nt = 0; nt < 4; ++nt) {
            short8 b = *(const short8*)&Wa1t[(size_t)(nt * 16 + m) * 256 + kc + q * 8];
            acc[nt] = __builtin_amdgcn_mfma_f32_16x16x32_bf16(a, b, acc[nt], 0, 0, 0);
        }
    }
    float part[4] = {0, 0, 0, 0};
    #pragma unroll
    for (int nt = 0; nt < 4; ++nt) {
        int col = nt * 16 + m;
        float ba1v = wbuf[S_BA1 + col];
        float wa2v = wbuf[S_WA2 + col];
        #pragma unroll
        for (int r = 0; r < 4; ++r)
            part[r] += prelu(acc[nt][r] + ba1v) * wa2v;
    }
    #pragma unroll
    for (int off = 1; off < 16; off <<= 1) {
        #pragma unroll
        for (int r = 0; r < 4; ++r)
            part[r] += __shfl_xor(part[r], off, 64);
    }
    if (m == 0) {
        float ba2v = wbuf[S_BA2];
        #pragma unroll
        for (int r = 0; r < 4; ++r) {
            int row = row0 + q * 4 + r;          // batch-major = b*NNODE+n
            float v = part[r] + ba2v;
            out[8 + row] = 1.f / (1.f + __expf(-v));
        }
    }
}

// ---------------- classification head (blocks 0-3) + diagnostics (block 4) ----------
__global__ __launch_bounds__(128) void k_logits(const float* __restrict__ pooled,
        const float* __restrict__ wbuf, const void* __restrict__ Wc1p,
        float* __restrict__ out,
        const u16* __restrict__ featb, const u16* __restrict__ gb,
        const int* __restrict__ row_ptr, const int* __restrict__ ei,
        const void* __restrict__ xsrc, int hostbad) {
    int tid = threadIdx.x;
    bool isbf = probe_x_bf16(xsrc);
    if (blockIdx.x == 4) {   // sampled diagnostics
        __shared__ float red[128];
        bool ei64 = probe_ei64(ei);
        float mx[2] = {0.f, 0.f};
        const u16* bufs[2] = {featb, gb};
        for (int qq = 0; qq < 2; ++qq) {
            const u16* p = bufs[qq];
            float m = 0.f;
            for (int i = tid; i < 2048; i += 128) {
                float v = u2f(p[i]);
                if (v != v) m = 1e30f;
                m = fmaxf(m, fabsf(v));
            }
            red[tid] = m;
            __syncthreads();
            for (int s2 = 64; s2 > 0; s2 >>= 1) {
                if (tid < s2) red[tid] = fmaxf(red[tid], red[tid + s2]);
                __syncthreads();
            }
            mx[qq] = red[0];
            __syncthreads();
        }
        if (tid == 0) {
            int fb = (mx[0] > 1e8f || mx[0] < 1e-6f) ? 1 : 0;
            int gbad = (mx[1] > 1e8f || mx[1] < 1e-6f) ? 1 : 0;
            int cb = (row_ptr[NNODE] != NEDGE + NNODE) ? 1 : 0;
            int code = 100 * fb + 400 * gbad + 800 * cb + 6400 * hostbad;
            if (code) {
                code += 1600 * (isbf ? 0 : 1);
                code += 3200 * (ei64 ? 1 : 0);
                for (int j = 0; j < 8; ++j) out[j] = (float)code;
            }
        }
        return;
    }
    __shared__ float pm[256];
    __shared__ float red4[4];
    int b = blockIdx.x;
    pm[tid] = pooled[b * 256 + tid] * (1.f / NNODE);
    pm[tid + 128] = pooled[b * 256 + tid + 128] * (1.f / NNODE);
    __syncthreads();
    float acc = wbuf[S_BC1 + tid];
    if (isbf) {
        const u16* w = (const u16*)Wc1p;
        #pragma unroll 4
        for (int k = 0; k < 256; ++k)
            acc += pm[k] * u2f(w[k * 128 + tid]);
    } else {
        const float* w = (const float*)Wc1p;
        #pragma unroll 4
        for (int k = 0; k < 256; ++k)
            acc += pm[k] * w[k * 128 + tid];
    }
    float hv = prelu(acc);
    float p0 = hv * wbuf[S_WC2 + tid * 2];
    float p1 = hv * wbuf[S_WC2 + tid * 2 + 1];
    #pragma unroll
    for (int off = 32; off > 0; off >>= 1) {
        p0 += __shfl_xor(p0, off, 64);
        p1 += __shfl_xor(p1, off, 64);
    }
    int wv = tid >> 6, lane = tid & 63;
    if (lane == 0) { red4[wv * 2] = p0; red4[wv * 2 + 1] = p1; }
    __syncthreads();
    if (tid < 2)
        out[b * 2 + tid] = red4[tid] + red4[2 + tid] + wbuf[S_BC2 + tid];
}

extern "C" void kernel_launch(void* const* d_in, const int* in_sizes, int n_in,
                              void* d_out, int out_size, void* d_ws, size_t ws_size,
                              hipStream_t stream) {
    const void* x  = d_in[0];
    const int*  ei = (const int*)d_in[1];
    float* out = (float*)d_out;

    WPtrs wp;
    for (int j = 0; j < 20; ++j) wp.p[j] = d_in[j + 2];

    char* ws = (char*)d_ws;
    size_t off = 0;
    auto alloc = [&](size_t bytes) -> void* {
        void* p = ws + off;
        off += (bytes + 255) & ~(size_t)255;
        return p;
    };
    float* wbuf    = (float*)alloc((size_t)S_TOTAL * 4);
    u16*   featb   = (u16*)  alloc((size_t)BATCH * NNODE * 64 * 2);
    u16*   xlb     = (u16*)  alloc((size_t)BATCH * NNODE * 256 * 2);
    u16*   gb      = (u16*)  alloc((size_t)BATCH * NNODE * 256 * 2);
    float* a_s     = (float*)alloc((size_t)BATCH * NNODE * 4 * 4);
    float* a_d     = (float*)alloc((size_t)BATCH * NNODE * 4 * 4);
    float* a_s2    = (float*)alloc((size_t)BATCH * NNODE * 4 * 4);
    float* a_d2    = (float*)alloc((size_t)BATCH * NNODE * 4 * 4);
    u16*   cw2r    = (u16*)alloc(6144 * 2);
    u16*   W0t     = (u16*)alloc(16384 * 2);
    u16*   W1t     = (u16*)alloc(65536 * 2);
    u16*   Wa1t    = (u16*)alloc(16384 * 2);
    // counts and pooled ADJACENT: one memset zeroes both
    int*   counts  = (int*)alloc(NNODE * 4);           // padded to 40192
    float* pooled  = (float*)alloc(BATCH * 256 * 4);   // 4096
    int*   row_ptr = (int*)alloc((NNODE + 1) * 4);
    int*   cur     = (int*)alloc(NNODE * 4);
    int*   col_src = (int*)alloc((NEDGE + NNODE) * 4);
    (void)ws_size; (void)out_size;

    int hostbad = (n_in != 22 || in_sizes[0] != BATCH * NNODE * TLEN ||
                   in_sizes[1] != 2 * NEDGE) ? 1 : 0;

    hipMemsetAsync(counts, 0, 40192 + 4096, stream);

    k_pre<<<PRE_TBLK + 9, 256, 0, stream>>>(wp, x, ei, wbuf, cw2r, W0t, W1t, Wa1t, counts);
    k_scan<<<1, 1024, 0, stream>>>(counts, cur, row_ptr);

    // fused conv + GAT-0 gemm + CSR fill (16 nodes/block, solo-wave conv)
    k_conv<<<BATCH * NNODE / 16, 256, 0, stream>>>(x, wbuf, cw2r, W0t, featb,
            xlb, a_s, a_d, ei, cur, col_src);

    // FUSED: layer-0 aggregation + layer-1 GEMM + layer-1 att scores
    // reads xlb/a_s/a_d -> writes gb (L1 feats), a_s2/a_d2
    k_agg_gemm<<<NNODE / 4, 512, 0, stream>>>(xlb, a_s, a_d, row_ptr, col_src,
            wbuf + S_B0, W1t, wbuf, gb, a_s2, a_d2);

    // layer-1 aggregation: reads gb/a_s2/a_d2 -> writes xlb (final g)
    k_agg<<<NNODE / 2, 256, 0, stream>>>(gb, a_s2, a_d2, row_ptr, col_src, wbuf + S_B1, xlb);

    // heads (read final g from xlb)
    k_attrpool<<<625 + 256, 256, 0, stream>>>(xlb, Wa1t, wbuf, out, pooled);
    k_logits<<<5, 128, 0, stream>>>(pooled, wbuf, wp.p[12], out, featb, xlb, row_ptr, ei, x, hostbad);
}